// Round 7
// baseline (1679.056 us; speedup 1.0000x reference)
//
#include <hip/hip_runtime.h>
#include <math.h>

#define LL   2048
#define BB   8
#define CC   32
#define CHH  256
#define HH   8
#define DD   6

typedef _Float16 h8 __attribute__((ext_vector_type(8)));
typedef float f4 __attribute__((ext_vector_type(4)));

// ---------------------------------------------------------------- encoder
__global__ __launch_bounds__(256) void k_enc(const float* __restrict__ x,
    const float* __restrict__ W, const float* __restrict__ bias,
    float* __restrict__ X) {
  int idx = blockIdx.x * 256 + threadIdx.x;          // B*32*L = 524288
  int l = idx & (LL - 1);
  int c = (idx >> 11) & 31;
  int b = idx >> 16;
  float s = bias[c];
#pragma unroll
  for (int i = 0; i < 6; ++i)
    s = fmaf(W[c * 6 + i], x[((size_t)b * 6 + i) * LL + l], s);
  X[idx] = s;
}

// ------------- pointwise conv with fused input-norm, f16 out, z = q/k/v
__global__ __launch_bounds__(256) void k_pw3(const float* __restrict__ Ysrc,
    const float* __restrict__ stIn, const float* __restrict__ ng,
    const float* __restrict__ nb, const float* __restrict__ Wq,
    const float* __restrict__ Wk, const float* __restrict__ Wv,
    _Float16* __restrict__ P3) {
  __shared__ float AB[64];
  int z  = blockIdx.y;
  int bx = blockIdx.x;
  int t  = threadIdx.x;
  int lt = bx & 7;
  int og = (bx >> 3) & 31;
  int b  = bx >> 8;
  if (t < 32) {
    float Aa = 1.f, Bb = 0.f;
    if (stIn) {
      float s1 = stIn[(b * 32 + t) * 2], s2 = stIn[(b * 32 + t) * 2 + 1];
      float mean = s1 * (1.f / 2048.f);
      float var  = s2 * (1.f / 2048.f) - mean * mean;
      float rs = rsqrtf(var + 1e-5f) * ng[t];
      Aa = rs; Bb = nb[t] - mean * rs;
    }
    AB[t] = Aa; AB[32 + t] = Bb;
  }
  __syncthreads();
  int l = lt * 256 + t;
  const float* W = (z == 0) ? Wq : (z == 1) ? Wk : Wv;
  const float* Xp = Ysrc + (size_t)b * CC * LL + l;
  float acc[8];
#pragma unroll
  for (int j = 0; j < 8; ++j) acc[j] = 0.f;
  for (int c = 0; c < CC; ++c) {
    float xv = fmaf(AB[c], Xp[(size_t)c * LL], AB[32 + c]);
#pragma unroll
    for (int j = 0; j < 8; ++j)
      acc[j] = fmaf(W[(og * 8 + j) * CC + c], xv, acc[j]);
  }
  _Float16* op = P3 + (size_t)z * 4194304 + ((size_t)b * CHH + og * 8) * LL + l;
#pragma unroll
  for (int j = 0; j < 8; ++j) op[(size_t)j * LL] = (_Float16)acc[j];
}

// ------------- fused depthwise conv3+conv15+gate+cvt+layout
// in: P3 [z][b][256ch][L] f16. out: z=0 Qt [bh][l][32c] (scaled by C^-.5*log2e),
// z=1 Kt same layout, z=2 Vt [bh][32c][l].
__global__ __launch_bounds__(256) void k_dwt3(const _Float16* __restrict__ P3,
    const float* __restrict__ d3q, const float* __restrict__ d15q, const float* __restrict__ gq,
    const float* __restrict__ d3k, const float* __restrict__ d15k, const float* __restrict__ gk,
    const float* __restrict__ d3v, const float* __restrict__ d15v, const float* __restrict__ gv,
    _Float16* __restrict__ Qt, _Float16* __restrict__ Kt, _Float16* __restrict__ Vt) {
  __shared__ __align__(16) char lds[9728 + 10240];
  int z  = blockIdx.y;
  int bx = blockIdx.x;
  int bh = bx >> 4, lt = bx & 15, l0 = lt * 128;
  int b = bh >> 3, h = bh & 7;
  int t = threadIdx.x;
  const float* w3p  = (z == 0) ? d3q  : (z == 1) ? d3k  : d3v;
  const float* w15p = (z == 0) ? d15q : (z == 1) ? d15k : d15v;
  const float* gp   = (z == 0) ? gq   : (z == 1) ? gk   : gv;

  {
    int row = t >> 3;
    int j0 = (t & 7) * 9;
    const unsigned int* grow = (const unsigned int*)
        (P3 + ((size_t)z * 8 + b) * (CHH * (size_t)LL) + ((size_t)h * 32 + row) * LL + (l0 - 8));
    unsigned int* lrow = (unsigned int*)(lds + row * 304);
#pragma unroll
    for (int k = 0; k < 9; ++k) {
      int j = j0 + k;
      int l = l0 - 8 + 2 * j;
      unsigned int v = 0;
      if (l >= 0 && l < LL) v = grow[j];
      lrow[j] = v;
    }
  }
  __syncthreads();

  int c = t & 31, cg = t >> 5;
  float wv[32];
  {
    const h8* wp = (const h8*)(lds + c * 304 + cg * 32);
#pragma unroll
    for (int q4 = 0; q4 < 4; ++q4) {
      h8 v = wp[q4];
#pragma unroll
      for (int e = 0; e < 8; ++e) wv[q4 * 8 + e] = (float)v[e];
    }
  }
  float r0 = gp[0], r1 = gp[1];
  float mx = fmaxf(r0, r1);
  float e0 = __expf(r0 - mx), e1 = __expf(r1 - mx);
  float gi = 1.f / (e0 + e1);
  float g0 = e0 * gi, g1 = e1 * gi;
  float sc = (z == 0) ? 0.2550765737f : 1.0f;   // C^-0.5 * log2(e) fold
  int ch = h * 32 + c;
  float w3r[3], w15r[15];
#pragma unroll
  for (int k = 0; k < 3; ++k)  w3r[k]  = w3p[ch * 3 + k];
#pragma unroll
  for (int k = 0; k < 15; ++k) w15r[k] = w15p[ch * 15 + k];

  h8 olo, ohi;
#pragma unroll
  for (int i = 0; i < 16; ++i) {
    float a = 0.f;
#pragma unroll
    for (int k = 0; k < 3; ++k) a = fmaf(w3r[k], wv[i + 7 + k], a);
    float s15 = 0.f;
#pragma unroll
    for (int k = 0; k < 15; ++k) s15 = fmaf(w15r[k], wv[i + 1 + k], s15);
    float val = (g0 * a + g1 * s15) * sc;
    if (i < 8) olo[i] = (_Float16)val; else ohi[i - 8] = (_Float16)val;
  }

  if (z == 2) {
    _Float16* dst = Vt + ((size_t)bh * 32 + c) * LL + l0 + cg * 16;
    *(h8*)dst = olo;
    *(h8*)(dst + 8) = ohi;
  } else {
    char* ot = lds + 9728;
#pragma unroll
    for (int i = 0; i < 16; ++i) {
      _Float16 v = (i < 8) ? olo[i] : ohi[i - 8];
      *(_Float16*)(ot + (cg * 16 + i) * 80 + c * 2) = v;
    }
    __syncthreads();
    _Float16* dst = ((z == 0) ? Qt : Kt) + ((size_t)bh * LL + l0) * 32;
    int l = t >> 1, hf = t & 1;
    uint4 a = *(uint4*)(ot + l * 80 + hf * 32);
    uint4 b2 = *(uint4*)(ot + l * 80 + hf * 32 + 16);
    *(uint4*)(dst + (size_t)l * 32 + hf * 16) = a;
    *(uint4*)(dst + (size_t)l * 32 + hf * 16 + 8) = b2;
  }
}

// ------------------------------------------------ MFMA flash attention (f16)
// 256 thr = 4 waves, 128 q/block (grid 16x64). 64-key tiles, reg-dbuf K/V
// staging; no-max exp2 softmax; P goes C-layout -> B-operand via 4-lane
// shuffle exchange (no LDS round-trip).
__global__ __launch_bounds__(256) void k_attn(
    const _Float16* __restrict__ Qt, const _Float16* __restrict__ Kt,
    const _Float16* __restrict__ Vt, float* __restrict__ Ob) {
  __shared__ __align__(16) char lds[19456];   // K: 2*5120 @0, V: 2*4608 @10240
  const int tid  = threadIdx.x;
  const int lane = tid & 63;
  const int w    = tid >> 6;
  const int g    = lane >> 4;
  const int ln   = lane & 15;
  const int a    = g & 1;
  const int b    = g >> 1;
  const int h2c  = (w >> 1) * 2;
  const int bh   = blockIdx.y;
  const int qb   = blockIdx.x;                // 0..15
  const _Float16* Qg = Qt + ((size_t)bh * LL + qb * 128) * 32;
  const _Float16* Kg = Kt + (size_t)bh * LL * 32;
  const _Float16* Vg = Vt + (size_t)bh * 32 * LL;

  h8 qf[2];
#pragma unroll
  for (int nt = 0; nt < 2; ++nt)
    qf[nt] = *(const h8*)(Qg + (size_t)(w * 32 + nt * 16 + ln) * 32 + g * 8);

  // prologue: stage K/V tile 0 into buf 0 (K: waves 0,2; V: waves 1,3)
  if ((w & 1) == 0) {
    const uint4* gk = (const uint4*)Kg;
    uint4 s0 = gk[h2c * 64 + lane];
    uint4 s1 = gk[(h2c + 1) * 64 + lane];
    *(uint4*)(lds + (h2c * 16 + (lane >> 2)) * 80 + (lane & 3) * 16) = s0;
    *(uint4*)(lds + ((h2c + 1) * 16 + (lane >> 2)) * 80 + (lane & 3) * 16) = s1;
  } else {
    int c0 = h2c * 8 + (lane >> 3);
    uint4 s0 = *(const uint4*)(Vg + (size_t)c0 * LL + (lane & 7) * 8);
    uint4 s1 = *(const uint4*)(Vg + (size_t)(c0 + 8) * LL + (lane & 7) * 8);
    *(uint4*)(lds + 10240 + c0 * 144 + (lane & 7) * 16) = s0;
    *(uint4*)(lds + 10240 + (c0 + 8) * 144 + (lane & 7) * 16) = s1;
  }
  __syncthreads();

  f4 o[2][2];                                  // [ct][nt]
#pragma unroll
  for (int ct = 0; ct < 2; ++ct)
#pragma unroll
    for (int nt = 0; nt < 2; ++nt) o[ct][nt] = (f4){0.f, 0.f, 0.f, 0.f};
  float lvp[2] = {0.f, 0.f};

  int p = 0;
  for (int it = 0; it < 32; ++it) {
    uint4 stg0, stg1;
    if (it < 31) {                             // prefetch next tile to regs
      int k0n = (it + 1) * 64;
      if ((w & 1) == 0) {
        const uint4* gk = (const uint4*)(Kg + (size_t)k0n * 32);
        stg0 = gk[h2c * 64 + lane];
        stg1 = gk[(h2c + 1) * 64 + lane];
      } else {
        int c0 = h2c * 8 + (lane >> 3);
        stg0 = *(const uint4*)(Vg + (size_t)c0 * LL + k0n + (lane & 7) * 8);
        stg1 = *(const uint4*)(Vg + (size_t)(c0 + 8) * LL + k0n + (lane & 7) * 8);
      }
    }
    const char* kb = lds + p * 5120;
    const char* vb = lds + 10240 + p * 4608;
    h8 kf[4];
#pragma unroll
    for (int mt = 0; mt < 4; ++mt)
      kf[mt] = *(const h8*)(kb + (mt * 16 + ln) * 80 + g * 16);
    h8 vf[2][2];
#pragma unroll
    for (int ch = 0; ch < 2; ++ch)
#pragma unroll
      for (int ct = 0; ct < 2; ++ct)
        vf[ch][ct] = *(const h8*)(vb + (ct * 16 + ln) * 144 + ch * 64 + g * 16);

#pragma unroll
    for (int nt = 0; nt < 2; ++nt) {
      // ---- S^T = K^T*Q: rows key=g*4+r (per mt), col q=ln
      f4 st[4];
#pragma unroll
      for (int mt = 0; mt < 4; ++mt) {
        f4 z = {0.f, 0.f, 0.f, 0.f};
        st[mt] = __builtin_amdgcn_mfma_f32_16x16x32_f16(kf[mt], qf[nt], z, 0, 0, 0);
      }
      // ---- exp2 + pack key-pairs to dwords
      unsigned pk[4][2];
#pragma unroll
      for (int mt = 0; mt < 4; ++mt) {
        float p0 = exp2f(st[mt][0]);
        float p1 = exp2f(st[mt][1]);
        float p2 = exp2f(st[mt][2]);
        float p3 = exp2f(st[mt][3]);
        lvp[nt] += (p0 + p1) + (p2 + p3);
        pk[mt][0] = __builtin_bit_cast(unsigned, __builtin_amdgcn_cvt_pkrtz(p0, p1));
        pk[mt][1] = __builtin_bit_cast(unsigned, __builtin_amdgcn_cvt_pkrtz(p2, p3));
      }
      // ---- C-layout -> B-operand via 4-lane (xor16/32/48) exchange
#pragma unroll
      for (int ch = 0; ch < 2; ++ch) {
        unsigned vs0 = b ? pk[2 * ch + 1][0] : pk[2 * ch][0];
        unsigned vs1 = b ? pk[2 * ch + 1][1] : pk[2 * ch][1];
        unsigned vo0 = b ? pk[2 * ch][0] : pk[2 * ch + 1][0];
        unsigned vo1 = b ? pk[2 * ch][1] : pk[2 * ch + 1][1];
        unsigned t16_0 = __shfl_xor(vs0, 16), t16_1 = __shfl_xor(vs1, 16);
        unsigned t32_0 = __shfl_xor(vo0, 32), t32_1 = __shfl_xor(vo1, 32);
        unsigned t48_0 = __shfl_xor(vo0, 48), t48_1 = __shfl_xor(vo1, 48);
        uint4 fr;
        fr.x = a ? (b ? t16_0 : t48_0) : (b ? t32_0 : vs0);
        fr.y = a ? (b ? t16_1 : t48_1) : (b ? t32_1 : vs1);
        fr.z = a ? (b ? vs0 : t32_0) : (b ? t48_0 : t16_0);
        fr.w = a ? (b ? vs1 : t32_1) : (b ? t48_1 : t16_1);
        h8 pf = __builtin_bit_cast(h8, fr);
#pragma unroll
        for (int ct = 0; ct < 2; ++ct)
          o[ct][nt] = __builtin_amdgcn_mfma_f32_16x16x32_f16(vf[ch][ct], pf,
                                                             o[ct][nt], 0, 0, 0);
      }
    }
    if (it < 31) {                             // store staged tile -> buf 1-p
      if ((w & 1) == 0) {
        char* kd = lds + (1 - p) * 5120;
        *(uint4*)(kd + (h2c * 16 + (lane >> 2)) * 80 + (lane & 3) * 16) = stg0;
        *(uint4*)(kd + ((h2c + 1) * 16 + (lane >> 2)) * 80 + (lane & 3) * 16) = stg1;
      } else {
        char* vd = lds + 10240 + (1 - p) * 4608;
        int c0 = h2c * 8 + (lane >> 3);
        *(uint4*)(vd + c0 * 144 + (lane & 7) * 16) = stg0;
        *(uint4*)(vd + (c0 + 8) * 144 + (lane & 7) * 16) = stg1;
      }
    }
    __syncthreads();
    p ^= 1;
  }

  // ---- epilogue: cross-group sum, normalize, write fp32 [bh][32c][L]
  float* out = Ob + (size_t)bh * (32 * LL);
#pragma unroll
  for (int nt = 0; nt < 2; ++nt) {
    float s = lvp[nt];
    s += __shfl_xor(s, 16);
    s += __shfl_xor(s, 32);
    float inv = 1.f / s;
    int qg = qb * 128 + w * 32 + nt * 16 + ln;
#pragma unroll
    for (int ct = 0; ct < 2; ++ct)
#pragma unroll
      for (int r = 0; r < 4; ++r)
        out[(size_t)(ct * 16 + g * 4 + r) * LL + qg] = o[ct][nt][r] * inv;
  }
}

// ---------- uni GEMM [32,256] + bias + norm-applied residual + stats out
__global__ __launch_bounds__(256) void k_uni_res(const float* __restrict__ AO,
    const float* __restrict__ W, const float* __restrict__ bias,
    const float* __restrict__ Xsrc, const float* __restrict__ stIn,
    const float* __restrict__ ng, const float* __restrict__ nb,
    float* __restrict__ Y, float* __restrict__ stOut) {
  __shared__ float AB[32];
  int t    = threadIdx.x;
  int half = blockIdx.x & 1;
  int lt   = (blockIdx.x >> 1) & 7;
  int b    = blockIdx.x >> 4;
  if (t < 16) {
    int c = half * 16 + t;
    float Aa = 1.f, Bb = 0.f;
    if (stIn) {
      float s1 = stIn[(b * 32 + c) * 2], s2 = stIn[(b * 32 + c) * 2 + 1];
      float mean = s1 * (1.f / 2048.f);
      float var  = s2 * (1.f / 2048.f) - mean * mean;
      float rs = rsqrtf(var + 1e-5f) * ng[c];
      Aa = rs; Bb = nb[c] - mean * rs;
    }
    AB[t] = Aa; AB[16 + t] = Bb;
  }
  __syncthreads();
  int l = lt * 256 + t;
  const float* ap = AO + (size_t)b * CHH * LL + l;
  float acc[16];
#pragma unroll
  for (int j = 0; j < 16; ++j) acc[j] = 0.f;
  for (int cc = 0; cc < CHH; cc += 4) {
    float a0 = ap[(size_t)(cc + 0) * LL];
    float a1 = ap[(size_t)(cc + 1) * LL];
    float a2 = ap[(size_t)(cc + 2) * LL];
    float a3 = ap[(size_t)(cc + 3) * LL];
#pragma unroll
    for (int j = 0; j < 16; ++j) {
      const float* wr = W + (half * 16 + j) * CHH + cc;
      acc[j] = fmaf(wr[0], a0, acc[j]);
      acc[j] = fmaf(wr[1], a1, acc[j]);
      acc[j] = fmaf(wr[2], a2, acc[j]);
      acc[j] = fmaf(wr[3], a3, acc[j]);
    }
  }
  int lane = t & 63;
#pragma unroll
  for (int j = 0; j < 16; ++j) {
    int c = half * 16 + j;
    size_t off = ((size_t)b * CC + c) * LL + l;
    float xn = fmaf(AB[j], Xsrc[off], AB[16 + j]);
    float y = acc[j] + bias[c] + xn;
    Y[off] = y;
    float s = y, ss = y * y;
#pragma unroll
    for (int o = 32; o; o >>= 1) { s += __shfl_down(s, o); ss += __shfl_down(ss, o); }
    if (lane == 0) {
      atomicAdd(&stOut[(b * 32 + c) * 2], s);
      atomicAdd(&stOut[(b * 32 + c) * 2 + 1], ss);
    }
  }
}

// ------ fused FFN: norm1-apply -> relu(W1 x+b1) -> W2+b2+residual -> stats2
__global__ __launch_bounds__(256) void k_ffn(const float* __restrict__ Y1,
    const float* __restrict__ stIn, const float* __restrict__ ng,
    const float* __restrict__ nb, const float* __restrict__ W1,
    const float* __restrict__ b1, const float* __restrict__ W2,
    const float* __restrict__ b2, float* __restrict__ Y2,
    float* __restrict__ stOut) {
  __shared__ float ps[128 * 33];
  __shared__ float AB[64];
  int bx = blockIdx.x;
  int b = bx >> 4;
  int l0 = (bx & 15) * 128;
  int t = threadIdx.x;
  if (t < 32) {
    float s1 = stIn[(b * 32 + t) * 2], s2 = stIn[(b * 32 + t) * 2 + 1];
    float mean = s1 * (1.f / 2048.f);
    float var  = s2 * (1.f / 2048.f) - mean * mean;
    float rs = rsqrtf(var + 1e-5f) * ng[t];
    AB[t] = rs; AB[32 + t] = nb[t] - mean * rs;
  }
  __syncthreads();
  int li = t & 127;
  int half = t >> 7;
  int l = l0 + li;
  const float* Xp = Y1 + (size_t)b * CC * LL + l;
  float xv[32];
#pragma unroll
  for (int c = 0; c < 32; ++c) xv[c] = fmaf(AB[c], Xp[(size_t)c * LL], AB[32 + c]);
  float acc[32];
#pragma unroll
  for (int c = 0; c < 32; ++c) acc[c] = 0.f;
  for (int o = half * 64; o < half * 64 + 64; ++o) {
    float hs = b1[o];
#pragma unroll
    for (int c = 0; c < 32; ++c) hs = fmaf(W1[o * 32 + c], xv[c], hs);
    hs = fmaxf(hs, 0.f);
#pragma unroll
    for (int c = 0; c < 32; ++c) acc[c] = fmaf(W2[c * 128 + o], hs, acc[c]);
  }
  if (half) {
#pragma unroll
    for (int c = 0; c < 32; ++c) ps[li * 33 + c] = acc[c];
  }
  __syncthreads();
  if (!half) {
    int lane = t & 63;
    float* Yp = Y2 + (size_t)b * CC * LL + l;
#pragma unroll
    for (int c = 0; c < 32; ++c) {
      float y = acc[c] + ps[li * 33 + c] + b2[c] + xv[c];
      Yp[(size_t)c * LL] = y;
      float s = y, ss = y * y;
#pragma unroll
      for (int o = 32; o; o >>= 1) { s += __shfl_down(s, o); ss += __shfl_down(ss, o); }
      if (lane == 0) {
        atomicAdd(&stOut[(b * 32 + c) * 2], s);
        atomicAdd(&stOut[(b * 32 + c) * 2 + 1], ss);
      }
    }
  }
}

// ------------------------------------- classifier with fused final norm
__global__ __launch_bounds__(256) void k_cls(const float* __restrict__ Y2,
    const float* __restrict__ stIn, const float* __restrict__ ng,
    const float* __restrict__ nb, const float* __restrict__ W,
    const float* __restrict__ bias, float* __restrict__ out) {
  __shared__ float AB[64];
  int idx = blockIdx.x * 256 + threadIdx.x;
  int l = idx & (LL - 1);
  int b = idx >> 11;
  int t = threadIdx.x;
  if (t < 32) {
    float s1 = stIn[(b * 32 + t) * 2], s2 = stIn[(b * 32 + t) * 2 + 1];
    float mean = s1 * (1.f / 2048.f);
    float var  = s2 * (1.f / 2048.f) - mean * mean;
    float rs = rsqrtf(var + 1e-5f) * ng[t];
    AB[t] = rs; AB[32 + t] = nb[t] - mean * rs;
  }
  __syncthreads();
  float s = bias[0];
#pragma unroll
  for (int c = 0; c < CC; ++c) {
    float xn = fmaf(AB[c], Y2[((size_t)b * CC + c) * LL + l], AB[32 + c]);
    s = fmaf(W[c], xn, s);
  }
  out[idx] = 1.f / (1.f + __expf(-s));
}

// ------------------------------------------------------------------ launch
extern "C" void kernel_launch(void* const* d_in, const int* in_sizes, int n_in,
                              void* d_out, int out_size, void* d_ws,
                              size_t ws_size, hipStream_t stream) {
  const float* x      = (const float*)d_in[0];
  const float* enc_W  = (const float*)d_in[1];
  const float* enc_b  = (const float*)d_in[2];
  const float* pw_q   = (const float*)d_in[3];
  const float* dw3_q  = (const float*)d_in[4];
  const float* dw15_q = (const float*)d_in[5];
  const float* gate_q = (const float*)d_in[6];
  const float* pw_k   = (const float*)d_in[7];
  const float* dw3_k  = (const float*)d_in[8];
  const float* dw15_k = (const float*)d_in[9];
  const float* gate_k = (const float*)d_in[10];
  const float* pw_v   = (const float*)d_in[11];
  const float* dw3_v  = (const float*)d_in[12];
  const float* dw15_v = (const float*)d_in[13];
  const float* gate_v = (const float*)d_in[14];
  const float* uni_W  = (const float*)d_in[15];
  const float* uni_b  = (const float*)d_in[16];
  const float* n1_g   = (const float*)d_in[17];
  const float* n1_b   = (const float*)d_in[18];
  const float* n2_g   = (const float*)d_in[19];
  const float* n2_b   = (const float*)d_in[20];
  const float* ffn_W1 = (const float*)d_in[21];
  const float* ffn_b1 = (const float*)d_in[22];
  const float* ffn_W2 = (const float*)d_in[23];
  const float* ffn_b2 = (const float*)d_in[24];
  const float* cls_W  = (const float*)d_in[25];
  const float* cls_b  = (const float*)d_in[26];

  float* ws = (float*)d_ws;
  float* E   = ws;                             // [B,32,L]
  float* Y1  = ws + 524288;                    // [B,32,L] pre-norm1
  float* Y2  = ws + 1048576;                   // [B,32,L] pre-norm2
  float* SB  = ws + 1572864;                   // stats [12][256][2]
  float* AO  = ws + 1579008;                   // [B,256,L] attn out
  _Float16* P3 = (_Float16*)(ws + 5773312);    // [3][B,256,L] f16
  _Float16* Qt = (_Float16*)(ws + 12064768);   // [64bh][L][32c]
  _Float16* Kt = (_Float16*)(ws + 14161920);
  _Float16* Vt = (_Float16*)(ws + 16259072);   // [64bh][32c][L]

  hipMemsetAsync(SB, 0, 12 * 512 * sizeof(float), stream);
  k_enc<<<2048, 256, 0, stream>>>(x, enc_W, enc_b, E);

  for (int d = 0; d < DD; ++d) {
    const float* Xsrc = (d == 0) ? E : Y2;
    const float* stPrev = (d == 0) ? nullptr : SB + (2 * (d - 1) + 1) * 512;
    const float* ngPrev = (d == 0) ? n2_g : n2_g + (d - 1) * 32;
    const float* nbPrev = (d == 0) ? n2_b : n2_b + (d - 1) * 32;
    float* st1 = SB + (2 * d) * 512;
    float* st2 = SB + (2 * d + 1) * 512;

    k_pw3<<<dim3(2048, 3), 256, 0, stream>>>(Xsrc, stPrev, ngPrev, nbPrev,
                                             pw_q + d * CHH * CC,
                                             pw_k + d * CHH * CC,
                                             pw_v + d * CHH * CC, P3);
    k_dwt3<<<dim3(1024, 3), 256, 0, stream>>>(P3,
        dw3_q + d * CHH * 3, dw15_q + d * CHH * 15, gate_q + d * 2,
        dw3_k + d * CHH * 3, dw15_k + d * CHH * 15, gate_k + d * 2,
        dw3_v + d * CHH * 3, dw15_v + d * CHH * 15, gate_v + d * 2,
        Qt, Kt, Vt);
    k_attn<<<dim3(16, 64), 256, 0, stream>>>(Qt, Kt, Vt, AO);
    k_uni_res<<<128, 256, 0, stream>>>(AO, uni_W + d * CC * CHH,
                                       uni_b + d * CC, Xsrc, stPrev,
                                       ngPrev, nbPrev, Y1, st1);
    k_ffn<<<128, 256, 0, stream>>>(Y1, st1, n1_g + d * 32, n1_b + d * 32,
                                   ffn_W1 + d * 128 * CC, ffn_b1 + d * 128,
                                   ffn_W2 + d * CC * 128, ffn_b2 + d * CC,
                                   Y2, st2);
  }

  k_cls<<<64, 256, 0, stream>>>(Y2, SB + 11 * 512, n2_g + 5 * 32,
                                n2_b + 5 * 32, cls_W, cls_b, (float*)d_out);
}

// Round 8
// 1437.063 us; speedup vs baseline: 1.1684x; 1.1684x over previous
//
#include <hip/hip_runtime.h>
#include <math.h>

#define LL   2048
#define BB   8
#define CC   32
#define CHH  256
#define HH   8
#define DD   6

typedef _Float16 h8 __attribute__((ext_vector_type(8)));
typedef _Float16 h4 __attribute__((ext_vector_type(4)));
typedef float f4 __attribute__((ext_vector_type(4)));

// ---------------------------------------------------------------- encoder
__global__ __launch_bounds__(256) void k_enc(const float* __restrict__ x,
    const float* __restrict__ W, const float* __restrict__ bias,
    float* __restrict__ X) {
  int idx = blockIdx.x * 256 + threadIdx.x;          // B*32*L = 524288
  int l = idx & (LL - 1);
  int c = (idx >> 11) & 31;
  int b = idx >> 16;
  float s = bias[c];
#pragma unroll
  for (int i = 0; i < 6; ++i)
    s = fmaf(W[c * 6 + i], x[((size_t)b * 6 + i) * LL + l], s);
  X[idx] = s;
}

// -------------------------------- pointwise conv, f16 out, z = tensor (q/k/v)
__global__ __launch_bounds__(256) void k_pw3(const float* __restrict__ X,
    const float* __restrict__ Wq, const float* __restrict__ Wk,
    const float* __restrict__ Wv, _Float16* __restrict__ P3) {
  int z  = blockIdx.y;
  int bx = blockIdx.x;
  int t  = threadIdx.x;
  int lt = bx & 7;
  int og = (bx >> 3) & 31;
  int b  = bx >> 8;
  int l  = lt * 256 + t;
  const float* W = (z == 0) ? Wq : (z == 1) ? Wk : Wv;
  const float* Xp = X + (size_t)b * CC * LL + l;
  float acc[8];
#pragma unroll
  for (int j = 0; j < 8; ++j) acc[j] = 0.f;
  for (int c = 0; c < CC; ++c) {
    float xv = Xp[(size_t)c * LL];
#pragma unroll
    for (int j = 0; j < 8; ++j)
      acc[j] = fmaf(W[(og * 8 + j) * CC + c], xv, acc[j]);
  }
  _Float16* op = P3 + (size_t)z * 4194304 + ((size_t)b * CHH + og * 8) * LL + l;
#pragma unroll
  for (int j = 0; j < 8; ++j) op[(size_t)j * LL] = (_Float16)acc[j];
}

// ------------- fused depthwise conv3+conv15+gate+cvt+layout
// in: P3 [z][b][256ch][L] f16. out: z=0 Qt [bh][l][32c] (scaled by C^-.5*log2e),
// z=1 Kt same layout, z=2 Vt [bh][32c][l].
__global__ __launch_bounds__(256) void k_dwt3(const _Float16* __restrict__ P3,
    const float* __restrict__ d3q, const float* __restrict__ d15q, const float* __restrict__ gq,
    const float* __restrict__ d3k, const float* __restrict__ d15k, const float* __restrict__ gk,
    const float* __restrict__ d3v, const float* __restrict__ d15v, const float* __restrict__ gv,
    _Float16* __restrict__ Qt, _Float16* __restrict__ Kt, _Float16* __restrict__ Vt) {
  __shared__ __align__(16) char lds[9728 + 10240];
  int z  = blockIdx.y;
  int bx = blockIdx.x;
  int bh = bx >> 4, lt = bx & 15, l0 = lt * 128;
  int b = bh >> 3, h = bh & 7;
  int t = threadIdx.x;
  const float* w3p  = (z == 0) ? d3q  : (z == 1) ? d3k  : d3v;
  const float* w15p = (z == 0) ? d15q : (z == 1) ? d15k : d15v;
  const float* gp   = (z == 0) ? gq   : (z == 1) ? gk   : gv;

  {
    int row = t >> 3;
    int j0 = (t & 7) * 9;
    const unsigned int* grow = (const unsigned int*)
        (P3 + ((size_t)z * 8 + b) * (CHH * (size_t)LL) + ((size_t)h * 32 + row) * LL + (l0 - 8));
    unsigned int* lrow = (unsigned int*)(lds + row * 304);
#pragma unroll
    for (int k = 0; k < 9; ++k) {
      int j = j0 + k;
      int l = l0 - 8 + 2 * j;
      unsigned int v = 0;
      if (l >= 0 && l < LL) v = grow[j];
      lrow[j] = v;
    }
  }
  __syncthreads();

  int c = t & 31, cg = t >> 5;
  float wv[32];
  {
    const h8* wp = (const h8*)(lds + c * 304 + cg * 32);
#pragma unroll
    for (int q4 = 0; q4 < 4; ++q4) {
      h8 v = wp[q4];
#pragma unroll
      for (int e = 0; e < 8; ++e) wv[q4 * 8 + e] = (float)v[e];
    }
  }
  float r0 = gp[0], r1 = gp[1];
  float mx = fmaxf(r0, r1);
  float e0 = __expf(r0 - mx), e1 = __expf(r1 - mx);
  float gi = 1.f / (e0 + e1);
  float g0 = e0 * gi, g1 = e1 * gi;
  float sc = (z == 0) ? 0.2550765737f : 1.0f;   // C^-0.5 * log2(e) fold
  int ch = h * 32 + c;
  float w3r[3], w15r[15];
#pragma unroll
  for (int k = 0; k < 3; ++k)  w3r[k]  = w3p[ch * 3 + k];
#pragma unroll
  for (int k = 0; k < 15; ++k) w15r[k] = w15p[ch * 15 + k];

  h8 olo, ohi;
#pragma unroll
  for (int i = 0; i < 16; ++i) {
    float a = 0.f;
#pragma unroll
    for (int k = 0; k < 3; ++k) a = fmaf(w3r[k], wv[i + 7 + k], a);
    float s15 = 0.f;
#pragma unroll
    for (int k = 0; k < 15; ++k) s15 = fmaf(w15r[k], wv[i + 1 + k], s15);
    float val = (g0 * a + g1 * s15) * sc;
    if (i < 8) olo[i] = (_Float16)val; else ohi[i - 8] = (_Float16)val;
  }

  if (z == 2) {
    _Float16* dst = Vt + ((size_t)bh * 32 + c) * LL + l0 + cg * 16;
    *(h8*)dst = olo;
    *(h8*)(dst + 8) = ohi;
  } else {
    char* ot = lds + 9728;
#pragma unroll
    for (int i = 0; i < 16; ++i) {
      _Float16 v = (i < 8) ? olo[i] : ohi[i - 8];
      *(_Float16*)(ot + (cg * 16 + i) * 80 + c * 2) = v;
    }
    __syncthreads();
    _Float16* dst = ((z == 0) ? Qt : Kt) + ((size_t)bh * LL + l0) * 32;
    int l = t >> 1, hf = t & 1;
    uint4 a = *(uint4*)(ot + l * 80 + hf * 32);
    uint4 b2 = *(uint4*)(ot + l * 80 + hf * 32 + 16);
    *(uint4*)(dst + (size_t)l * 32 + hf * 16) = a;
    *(uint4*)(dst + (size_t)l * 32 + hf * 16 + 8) = b2;
  }
}

// ------------------------------------------------ MFMA flash attention (f16)
// 256 thr = 4 waves, 256 q/block (grid 8x64). 64-key tiles, reg-dbuf K/V
// staging; no-max exp2 softmax; P -> per-wave LDS (stride-72 rows: b64 writes
// are 2-way = free), PV chunked at 32 keys to shrink LDS -> 4 blocks/CU.
// LDS map: K dbuf 2*5120 @0 (stride 80); V dbuf 2*4608 @10240 (stride 144);
//          P 4 waves * 4608 @19456 (stride 72). Total 37888.
#define KOFF 0
#define VOFF 10240
#define POFF 19456
__global__ __launch_bounds__(256, 2) void k_attn(
    const _Float16* __restrict__ Qt, const _Float16* __restrict__ Kt,
    const _Float16* __restrict__ Vt, _Float16* __restrict__ Ob) {
  __shared__ __align__(16) char lds[37888];
  const int tid  = threadIdx.x;
  const int lane = tid & 63;
  const int w    = tid >> 6;
  const int g    = lane >> 4;
  const int ln   = lane & 15;
  const int h2c  = (w >> 1) * 2;
  const int bh   = blockIdx.y;
  const int qb   = blockIdx.x;
  const _Float16* Qg = Qt + ((size_t)bh * LL + qb * 256) * 32;
  const _Float16* Kg = Kt + (size_t)bh * LL * 32;
  const _Float16* Vg = Vt + (size_t)bh * 32 * LL;

  // Q fragments from global (B operand: [k=c][n=q])
  h8 qf[4];
#pragma unroll
  for (int nt = 0; nt < 4; ++nt)
    qf[nt] = *(const h8*)(Qg + (size_t)(w * 64 + nt * 16 + ln) * 32 + g * 8);

  // prologue: stage K/V tile 0 into buf 0 (K: waves 0,2; V: waves 1,3)
  if ((w & 1) == 0) {
    const uint4* gk = (const uint4*)Kg;
    uint4 s0 = gk[h2c * 64 + lane];
    uint4 s1 = gk[(h2c + 1) * 64 + lane];
    *(uint4*)(lds + KOFF + (h2c * 16 + (lane >> 2)) * 80 + (lane & 3) * 16) = s0;
    *(uint4*)(lds + KOFF + ((h2c + 1) * 16 + (lane >> 2)) * 80 + (lane & 3) * 16) = s1;
  } else {
    int c0 = h2c * 8 + (lane >> 3);
    uint4 s0 = *(const uint4*)(Vg + (size_t)c0 * LL + (lane & 7) * 8);
    uint4 s1 = *(const uint4*)(Vg + (size_t)(c0 + 8) * LL + (lane & 7) * 8);
    *(uint4*)(lds + VOFF + c0 * 144 + (lane & 7) * 16) = s0;
    *(uint4*)(lds + VOFF + (c0 + 8) * 144 + (lane & 7) * 16) = s1;
  }
  __syncthreads();

  f4 o[2][4];
#pragma unroll
  for (int ct = 0; ct < 2; ++ct)
#pragma unroll
    for (int nt = 0; nt < 4; ++nt) o[ct][nt] = (f4){0.f, 0.f, 0.f, 0.f};
  float lvp[4] = {0.f, 0.f, 0.f, 0.f};

  char* pw = lds + POFF + w * 4608;
  int p = 0;
  for (int it = 0; it < 32; ++it) {
    uint4 stg0, stg1;
    if (it < 31) {                             // prefetch next tile to regs
      int k0n = (it + 1) * 64;
      if ((w & 1) == 0) {
        const uint4* gk = (const uint4*)(Kg + (size_t)k0n * 32);
        stg0 = gk[h2c * 64 + lane];
        stg1 = gk[(h2c + 1) * 64 + lane];
      } else {
        int c0 = h2c * 8 + (lane >> 3);
        stg0 = *(const uint4*)(Vg + (size_t)c0 * LL + k0n + (lane & 7) * 8);
        stg1 = *(const uint4*)(Vg + (size_t)(c0 + 8) * LL + k0n + (lane & 7) * 8);
      }
    }
    const char* kb = lds + KOFF + p * 5120;
    const char* vb = lds + VOFF + p * 4608;
#pragma unroll
    for (int chunk = 0; chunk < 2; ++chunk) {
      // ---- S^T = K^T*Q for this 32-key half
      f4 st[2][4];
#pragma unroll
      for (int mt2 = 0; mt2 < 2; ++mt2) {
        h8 kf = *(const h8*)(kb + ((chunk * 2 + mt2) * 16 + ln) * 80 + g * 16);
#pragma unroll
        for (int nt = 0; nt < 4; ++nt) {
          f4 z = {0.f, 0.f, 0.f, 0.f};
          st[mt2][nt] = __builtin_amdgcn_mfma_f32_16x16x32_f16(kf, qf[nt], z, 0, 0, 0);
        }
      }
      // ---- exp2 + pack + P write (rows = wave-local q, stride 72)
#pragma unroll
      for (int mt2 = 0; mt2 < 2; ++mt2)
#pragma unroll
        for (int nt = 0; nt < 4; ++nt) {
          float p0 = exp2f(st[mt2][nt][0]);
          float p1 = exp2f(st[mt2][nt][1]);
          float p2 = exp2f(st[mt2][nt][2]);
          float p3 = exp2f(st[mt2][nt][3]);
          lvp[nt] += (p0 + p1) + (p2 + p3);
          unsigned lo = __builtin_bit_cast(unsigned, __builtin_amdgcn_cvt_pkrtz(p0, p1));
          unsigned hi = __builtin_bit_cast(unsigned, __builtin_amdgcn_cvt_pkrtz(p2, p3));
          uint2 pk; pk.x = lo; pk.y = hi;
          *(uint2*)(pw + (nt * 16 + ln) * 72 + mt2 * 32 + g * 8) = pk;
        }
      // ---- O += V * P^T (kdim = 32 keys of this chunk)
      h8 vf[2];
#pragma unroll
      for (int ct = 0; ct < 2; ++ct)
        vf[ct] = *(const h8*)(vb + (ct * 16 + ln) * 144 + chunk * 64 + g * 16);
#pragma unroll
      for (int nt = 0; nt < 4; ++nt) {
        h4 plo = *(const h4*)(pw + (nt * 16 + ln) * 72 + g * 16);
        h4 phi = *(const h4*)(pw + (nt * 16 + ln) * 72 + g * 16 + 8);
        h8 pf;
        pf[0] = plo[0]; pf[1] = plo[1]; pf[2] = plo[2]; pf[3] = plo[3];
        pf[4] = phi[0]; pf[5] = phi[1]; pf[6] = phi[2]; pf[7] = phi[3];
#pragma unroll
        for (int ct = 0; ct < 2; ++ct)
          o[ct][nt] = __builtin_amdgcn_mfma_f32_16x16x32_f16(vf[ct], pf,
                                                             o[ct][nt], 0, 0, 0);
      }
    }
    if (it < 31) {                             // store staged tile -> buf 1-p
      if ((w & 1) == 0) {
        char* kd = lds + KOFF + (1 - p) * 5120;
        *(uint4*)(kd + (h2c * 16 + (lane >> 2)) * 80 + (lane & 3) * 16) = stg0;
        *(uint4*)(kd + ((h2c + 1) * 16 + (lane >> 2)) * 80 + (lane & 3) * 16) = stg1;
      } else {
        char* vd = lds + VOFF + (1 - p) * 4608;
        int c0 = h2c * 8 + (lane >> 3);
        *(uint4*)(vd + c0 * 144 + (lane & 7) * 16) = stg0;
        *(uint4*)(vd + (c0 + 8) * 144 + (lane & 7) * 16) = stg1;
      }
    }
    __syncthreads();
    p ^= 1;
  }

  // ---- epilogue: cross-group sum, normalize, write f16 [bh][32c][L]
  _Float16* out = Ob + (size_t)bh * (32 * LL);
#pragma unroll
  for (int nt = 0; nt < 4; ++nt) {
    float s = lvp[nt];
    s += __shfl_xor(s, 16);
    s += __shfl_xor(s, 32);
    float inv = 1.f / s;
    int qg = qb * 256 + w * 64 + nt * 16 + ln;
#pragma unroll
    for (int ct = 0; ct < 2; ++ct)
#pragma unroll
      for (int r = 0; r < 4; ++r)
        out[(size_t)(ct * 16 + g * 4 + r) * LL + qg] = (_Float16)(o[ct][nt][r] * inv);
  }
}

// ------------------- uni GEMM [32,256] f16-in + bias + residual (fp32 out)
__global__ __launch_bounds__(256) void k_uni_res(const _Float16* __restrict__ AO,
    const float* __restrict__ W, const float* __restrict__ bias,
    const float* __restrict__ Xin, float* __restrict__ Y) {
  int t    = threadIdx.x;
  int half = blockIdx.x & 1;
  int lt   = (blockIdx.x >> 1) & 7;
  int b    = blockIdx.x >> 4;
  int l    = lt * 256 + t;
  const _Float16* ap = AO + (size_t)b * CHH * LL + l;
  float acc[16];
#pragma unroll
  for (int j = 0; j < 16; ++j) acc[j] = 0.f;
  for (int cc = 0; cc < CHH; cc += 4) {
    float a0 = (float)ap[(size_t)(cc + 0) * LL];
    float a1 = (float)ap[(size_t)(cc + 1) * LL];
    float a2 = (float)ap[(size_t)(cc + 2) * LL];
    float a3 = (float)ap[(size_t)(cc + 3) * LL];
#pragma unroll
    for (int j = 0; j < 16; ++j) {
      const float* wr = W + (half * 16 + j) * CHH + cc;
      acc[j] = fmaf(wr[0], a0, acc[j]);
      acc[j] = fmaf(wr[1], a1, acc[j]);
      acc[j] = fmaf(wr[2], a2, acc[j]);
      acc[j] = fmaf(wr[3], a3, acc[j]);
    }
  }
#pragma unroll
  for (int j = 0; j < 16; ++j) {
    int c = half * 16 + j;
    size_t o = ((size_t)b * CC + c) * LL + l;
    Y[o] = acc[j] + bias[c] + Xin[o];
  }
}

// ---------------------------------------------------------- instance norm
__global__ __launch_bounds__(256) void k_inorm(const float* __restrict__ Y,
    float* __restrict__ X, const float* __restrict__ g,
    const float* __restrict__ bt) {
  __shared__ float red[8];
  int row = blockIdx.x;
  int c = row & 31;
  const float* y = Y + (size_t)row * LL;
  float v[8];
  float s = 0.f, ss = 0.f;
#pragma unroll
  for (int i = 0; i < 8; ++i) {
    v[i] = y[threadIdx.x + 256 * i];
    s += v[i];
    ss = fmaf(v[i], v[i], ss);
  }
#pragma unroll
  for (int off = 32; off; off >>= 1) {
    s  += __shfl_down(s, off);
    ss += __shfl_down(ss, off);
  }
  int wid = threadIdx.x >> 6;
  if ((threadIdx.x & 63) == 0) { red[wid * 2] = s; red[wid * 2 + 1] = ss; }
  __syncthreads();
  if (threadIdx.x == 0) {
    red[0] = red[0] + red[2] + red[4] + red[6];
    red[1] = red[1] + red[3] + red[5] + red[7];
  }
  __syncthreads();
  float mean = red[0] * (1.f / LL);
  float var  = red[1] * (1.f / LL) - mean * mean;
  float rs = rsqrtf(var + 1e-5f) * g[c];
  float bb = bt[c];
#pragma unroll
  for (int i = 0; i < 8; ++i)
    X[(size_t)row * LL + threadIdx.x + 256 * i] = (v[i] - mean) * rs + bb;
}

// ---------------------- fused FFN: relu(W1 x + b1) -> W2 + b2 + residual
__global__ __launch_bounds__(256) void k_ffn(const float* __restrict__ X,
    const float* __restrict__ W1, const float* __restrict__ b1,
    const float* __restrict__ W2, const float* __restrict__ b2,
    float* __restrict__ Y) {
  __shared__ float ps[128 * 33];
  int bx = blockIdx.x;
  int b = bx >> 4;
  int l0 = (bx & 15) * 128;
  int t = threadIdx.x;
  int li = t & 127;
  int half = t >> 7;
  int l = l0 + li;
  const float* Xp = X + (size_t)b * CC * LL + l;
  float xv[32];
#pragma unroll
  for (int c = 0; c < 32; ++c) xv[c] = Xp[(size_t)c * LL];
  float acc[32];
#pragma unroll
  for (int c = 0; c < 32; ++c) acc[c] = 0.f;
  for (int o = half * 64; o < half * 64 + 64; ++o) {
    float hs = b1[o];
#pragma unroll
    for (int c = 0; c < 32; ++c) hs = fmaf(W1[o * 32 + c], xv[c], hs);
    hs = fmaxf(hs, 0.f);
#pragma unroll
    for (int c = 0; c < 32; ++c) acc[c] = fmaf(W2[c * 128 + o], hs, acc[c]);
  }
  if (half) {
#pragma unroll
    for (int c = 0; c < 32; ++c) ps[li * 33 + c] = acc[c];
  }
  __syncthreads();
  if (!half) {
    float* Yp = Y + (size_t)b * CC * LL + l;
#pragma unroll
    for (int c = 0; c < 32; ++c)
      Yp[(size_t)c * LL] = acc[c] + ps[li * 33 + c] + b2[c] + xv[c];
  }
}

// ------------------------------------------------------------- classifier
__global__ __launch_bounds__(256) void k_cls(const float* __restrict__ X,
    const float* __restrict__ W, const float* __restrict__ bias,
    float* __restrict__ out) {
  int idx = blockIdx.x * 256 + threadIdx.x;
  int l = idx & (LL - 1);
  int b = idx >> 11;
  float s = bias[0];
#pragma unroll
  for (int c = 0; c < CC; ++c)
    s = fmaf(W[c], X[((size_t)b * CC + c) * LL + l], s);
  out[idx] = 1.f / (1.f + __expf(-s));
}

// ------------------------------------------------------------------ launch
extern "C" void kernel_launch(void* const* d_in, const int* in_sizes, int n_in,
                              void* d_out, int out_size, void* d_ws,
                              size_t ws_size, hipStream_t stream) {
  const float* x      = (const float*)d_in[0];
  const float* enc_W  = (const float*)d_in[1];
  const float* enc_b  = (const float*)d_in[2];
  const float* pw_q   = (const float*)d_in[3];
  const float* dw3_q  = (const float*)d_in[4];
  const float* dw15_q = (const float*)d_in[5];
  const float* gate_q = (const float*)d_in[6];
  const float* pw_k   = (const float*)d_in[7];
  const float* dw3_k  = (const float*)d_in[8];
  const float* dw15_k = (const float*)d_in[9];
  const float* gate_k = (const float*)d_in[10];
  const float* pw_v   = (const float*)d_in[11];
  const float* dw3_v  = (const float*)d_in[12];
  const float* dw15_v = (const float*)d_in[13];
  const float* gate_v = (const float*)d_in[14];
  const float* uni_W  = (const float*)d_in[15];
  const float* uni_b  = (const float*)d_in[16];
  const float* n1_g   = (const float*)d_in[17];
  const float* n1_b   = (const float*)d_in[18];
  const float* n2_g   = (const float*)d_in[19];
  const float* n2_b   = (const float*)d_in[20];
  const float* ffn_W1 = (const float*)d_in[21];
  const float* ffn_b1 = (const float*)d_in[22];
  const float* ffn_W2 = (const float*)d_in[23];
  const float* ffn_b2 = (const float*)d_in[24];
  const float* cls_W  = (const float*)d_in[25];
  const float* cls_b  = (const float*)d_in[26];

  float* ws = (float*)d_ws;
  float* X   = ws;                             // [B,32,L] fp32
  float* Y   = ws + 524288;                    // [B,32,L] fp32
  _Float16* AO = (_Float16*)(ws + 1048576);    // [B,256,L] f16 attn out
  _Float16* P3 = (_Float16*)(ws + 3145728);    // [3][B,256,L] f16 pw out
  _Float16* Qt = (_Float16*)(ws + 9437184);    // [64bh][L][32c] f16
  _Float16* Kt = (_Float16*)(ws + 11534336);   // [64bh][L][32c] f16
  _Float16* Vt = (_Float16*)(ws + 13631488);   // [64bh][32c][L] f16

  k_enc<<<2048, 256, 0, stream>>>(x, enc_W, enc_b, X);

  for (int d = 0; d < DD; ++d) {
    k_pw3<<<dim3(2048, 3), 256, 0, stream>>>(X, pw_q + d * CHH * CC,
                                             pw_k + d * CHH * CC,
                                             pw_v + d * CHH * CC, P3);
    k_dwt3<<<dim3(1024, 3), 256, 0, stream>>>(P3,
        dw3_q + d * CHH * 3, dw15_q + d * CHH * 15, gate_q + d * 2,
        dw3_k + d * CHH * 3, dw15_k + d * CHH * 15, gate_k + d * 2,
        dw3_v + d * CHH * 3, dw15_v + d * CHH * 15, gate_v + d * 2,
        Qt, Kt, Vt);
    k_attn<<<dim3(8, 64), 256, 0, stream>>>(Qt, Kt, Vt, AO);
    k_uni_res<<<128, 256, 0, stream>>>(AO, uni_W + d * CC * CHH,
                                       uni_b + d * CC, X, Y);
    k_inorm<<<256, 256, 0, stream>>>(Y, X, n1_g + d * CC, n1_b + d * CC);
    k_ffn<<<128, 256, 0, stream>>>(X, ffn_W1 + d * 128 * CC, ffn_b1 + d * 128,
                                   ffn_W2 + d * CC * 128, ffn_b2 + d * CC, Y);
    k_inorm<<<256, 256, 0, stream>>>(Y, X, n2_g + d * CC, n2_b + d * CC);
  }

  k_cls<<<64, 256, 0, stream>>>(X, cls_W, cls_b, (float*)d_out);
}

// Round 9
// 1390.089 us; speedup vs baseline: 1.2079x; 1.0338x over previous
//
#include <hip/hip_runtime.h>
#include <math.h>

#define LL   2048
#define BB   8
#define CC   32
#define CHH  256
#define HH   8
#define DD   6

typedef _Float16 h8 __attribute__((ext_vector_type(8)));
typedef _Float16 h4 __attribute__((ext_vector_type(4)));
typedef float f4 __attribute__((ext_vector_type(4)));

// ---------------------------------------------------------------- encoder
__global__ __launch_bounds__(256) void k_enc(const float* __restrict__ x,
    const float* __restrict__ W, const float* __restrict__ bias,
    float* __restrict__ X) {
  int idx = blockIdx.x * 256 + threadIdx.x;          // B*32*L = 524288
  int l = idx & (LL - 1);
  int c = (idx >> 11) & 31;
  int b = idx >> 16;
  float s = bias[c];
#pragma unroll
  for (int i = 0; i < 6; ++i)
    s = fmaf(W[c * 6 + i], x[((size_t)b * 6 + i) * LL + l], s);
  X[idx] = s;
}

// -------------------------------- pointwise conv, f16 out, z = tensor (q/k/v)
__global__ __launch_bounds__(256) void k_pw3(const float* __restrict__ X,
    const float* __restrict__ Wq, const float* __restrict__ Wk,
    const float* __restrict__ Wv, _Float16* __restrict__ P3) {
  int z  = blockIdx.y;
  int bx = blockIdx.x;
  int t  = threadIdx.x;
  int lt = bx & 7;
  int og = (bx >> 3) & 31;
  int b  = bx >> 8;
  int l  = lt * 256 + t;
  const float* W = (z == 0) ? Wq : (z == 1) ? Wk : Wv;
  const float* Xp = X + (size_t)b * CC * LL + l;
  float acc[8];
#pragma unroll
  for (int j = 0; j < 8; ++j) acc[j] = 0.f;
  for (int c = 0; c < CC; ++c) {
    float xv = Xp[(size_t)c * LL];
#pragma unroll
    for (int j = 0; j < 8; ++j)
      acc[j] = fmaf(W[(og * 8 + j) * CC + c], xv, acc[j]);
  }
  _Float16* op = P3 + (size_t)z * 4194304 + ((size_t)b * CHH + og * 8) * LL + l;
#pragma unroll
  for (int j = 0; j < 8; ++j) op[(size_t)j * LL] = (_Float16)acc[j];
}

// ------------- fused depthwise conv3+conv15+gate+cvt+layout
// in: P3 [z][b][256ch][L] f16. out: z=0 Qt [bh][l][32c] (scaled by C^-.5*log2e),
// z=1 Kt same layout, z=2 Vt [bh][32c][l].
__global__ __launch_bounds__(256) void k_dwt3(const _Float16* __restrict__ P3,
    const float* __restrict__ d3q, const float* __restrict__ d15q, const float* __restrict__ gq,
    const float* __restrict__ d3k, const float* __restrict__ d15k, const float* __restrict__ gk,
    const float* __restrict__ d3v, const float* __restrict__ d15v, const float* __restrict__ gv,
    _Float16* __restrict__ Qt, _Float16* __restrict__ Kt, _Float16* __restrict__ Vt) {
  __shared__ __align__(16) char lds[9728 + 10240];
  int z  = blockIdx.y;
  int bx = blockIdx.x;
  int bh = bx >> 4, lt = bx & 15, l0 = lt * 128;
  int b = bh >> 3, h = bh & 7;
  int t = threadIdx.x;
  const float* w3p  = (z == 0) ? d3q  : (z == 1) ? d3k  : d3v;
  const float* w15p = (z == 0) ? d15q : (z == 1) ? d15k : d15v;
  const float* gp   = (z == 0) ? gq   : (z == 1) ? gk   : gv;

  {
    int row = t >> 3;
    int j0 = (t & 7) * 9;
    const unsigned int* grow = (const unsigned int*)
        (P3 + ((size_t)z * 8 + b) * (CHH * (size_t)LL) + ((size_t)h * 32 + row) * LL + (l0 - 8));
    unsigned int* lrow = (unsigned int*)(lds + row * 304);
#pragma unroll
    for (int k = 0; k < 9; ++k) {
      int j = j0 + k;
      int l = l0 - 8 + 2 * j;
      unsigned int v = 0;
      if (l >= 0 && l < LL) v = grow[j];
      lrow[j] = v;
    }
  }
  __syncthreads();

  int c = t & 31, cg = t >> 5;
  float wv[32];
  {
    const h8* wp = (const h8*)(lds + c * 304 + cg * 32);
#pragma unroll
    for (int q4 = 0; q4 < 4; ++q4) {
      h8 v = wp[q4];
#pragma unroll
      for (int e = 0; e < 8; ++e) wv[q4 * 8 + e] = (float)v[e];
    }
  }
  float r0 = gp[0], r1 = gp[1];
  float mx = fmaxf(r0, r1);
  float e0 = __expf(r0 - mx), e1 = __expf(r1 - mx);
  float gi = 1.f / (e0 + e1);
  float g0 = e0 * gi, g1 = e1 * gi;
  float sc = (z == 0) ? 0.2550765737f : 1.0f;   // C^-0.5 * log2(e) fold
  int ch = h * 32 + c;
  float w3r[3], w15r[15];
#pragma unroll
  for (int k = 0; k < 3; ++k)  w3r[k]  = w3p[ch * 3 + k];
#pragma unroll
  for (int k = 0; k < 15; ++k) w15r[k] = w15p[ch * 15 + k];

  h8 olo, ohi;
#pragma unroll
  for (int i = 0; i < 16; ++i) {
    float a = 0.f;
#pragma unroll
    for (int k = 0; k < 3; ++k) a = fmaf(w3r[k], wv[i + 7 + k], a);
    float s15 = 0.f;
#pragma unroll
    for (int k = 0; k < 15; ++k) s15 = fmaf(w15r[k], wv[i + 1 + k], s15);
    float val = (g0 * a + g1 * s15) * sc;
    if (i < 8) olo[i] = (_Float16)val; else ohi[i - 8] = (_Float16)val;
  }

  if (z == 2) {
    _Float16* dst = Vt + ((size_t)bh * 32 + c) * LL + l0 + cg * 16;
    *(h8*)dst = olo;
    *(h8*)(dst + 8) = ohi;
  } else {
    char* ot = lds + 9728;
#pragma unroll
    for (int i = 0; i < 16; ++i) {
      _Float16 v = (i < 8) ? olo[i] : ohi[i - 8];
      *(_Float16*)(ot + (cg * 16 + i) * 80 + c * 2) = v;
    }
    __syncthreads();
    _Float16* dst = ((z == 0) ? Qt : Kt) + ((size_t)bh * LL + l0) * 32;
    int l = t >> 1, hf = t & 1;
    uint4 a = *(uint4*)(ot + l * 80 + hf * 32);
    uint4 b2 = *(uint4*)(ot + l * 80 + hf * 32 + 16);
    *(uint4*)(dst + (size_t)l * 32 + hf * 16) = a;
    *(uint4*)(dst + (size_t)l * 32 + hf * 16 + 8) = b2;
  }
}

// ------------------------------------------------ MFMA flash attention (f16)
// Key-split x2: grid (8 qb, 2 kseg, 64 bh) = 1024 blocks -> 4 blocks/CU.
// Each block: 256 q x 1024 keys (16 64-key tiles, reg-dbuf staging).
// No-max exp2 softmax => exact cross-segment merge: partial unnormalized O
// (f16) + per-q partial sum; k_comb merges.
#define KOFF 0
#define VOFF 10240
#define POFF 19456
__global__ __launch_bounds__(256, 4) void k_attn(
    const _Float16* __restrict__ Qt, const _Float16* __restrict__ Kt,
    const _Float16* __restrict__ Vt, _Float16* __restrict__ OP,
    float* __restrict__ LS) {
  __shared__ __align__(16) char lds[37888];
  const int tid  = threadIdx.x;
  const int lane = tid & 63;
  const int w    = tid >> 6;
  const int g    = lane >> 4;
  const int ln   = lane & 15;
  const int h2c  = (w >> 1) * 2;
  const int qb   = blockIdx.x;                 // 0..7
  const int ks   = blockIdx.y;                 // 0..1
  const int bh   = blockIdx.z;                 // 0..63
  const _Float16* Qg = Qt + ((size_t)bh * LL + qb * 256) * 32;
  const _Float16* Kg = Kt + ((size_t)bh * LL + ks * 1024) * 32;
  const _Float16* Vg = Vt + (size_t)bh * 32 * LL + ks * 1024;

  // Q fragments from global (B operand: [k=c][n=q])
  h8 qf[4];
#pragma unroll
  for (int nt = 0; nt < 4; ++nt)
    qf[nt] = *(const h8*)(Qg + (size_t)(w * 64 + nt * 16 + ln) * 32 + g * 8);

  // prologue: stage K/V tile 0 into buf 0 (K: waves 0,2; V: waves 1,3)
  if ((w & 1) == 0) {
    const uint4* gk = (const uint4*)Kg;
    uint4 s0 = gk[h2c * 64 + lane];
    uint4 s1 = gk[(h2c + 1) * 64 + lane];
    *(uint4*)(lds + KOFF + (h2c * 16 + (lane >> 2)) * 80 + (lane & 3) * 16) = s0;
    *(uint4*)(lds + KOFF + ((h2c + 1) * 16 + (lane >> 2)) * 80 + (lane & 3) * 16) = s1;
  } else {
    int c0 = h2c * 8 + (lane >> 3);
    uint4 s0 = *(const uint4*)(Vg + (size_t)c0 * LL + (lane & 7) * 8);
    uint4 s1 = *(const uint4*)(Vg + (size_t)(c0 + 8) * LL + (lane & 7) * 8);
    *(uint4*)(lds + VOFF + c0 * 144 + (lane & 7) * 16) = s0;
    *(uint4*)(lds + VOFF + (c0 + 8) * 144 + (lane & 7) * 16) = s1;
  }
  __syncthreads();

  f4 o[2][4];
#pragma unroll
  for (int ct = 0; ct < 2; ++ct)
#pragma unroll
    for (int nt = 0; nt < 4; ++nt) o[ct][nt] = (f4){0.f, 0.f, 0.f, 0.f};
  float lvp[4] = {0.f, 0.f, 0.f, 0.f};

  char* pw = lds + POFF + w * 4608;
  int p = 0;
  for (int it = 0; it < 16; ++it) {
    uint4 stg0, stg1;
    if (it < 15) {                             // prefetch next tile to regs
      int k0n = (it + 1) * 64;
      if ((w & 1) == 0) {
        const uint4* gk = (const uint4*)(Kg + (size_t)k0n * 32);
        stg0 = gk[h2c * 64 + lane];
        stg1 = gk[(h2c + 1) * 64 + lane];
      } else {
        int c0 = h2c * 8 + (lane >> 3);
        stg0 = *(const uint4*)(Vg + (size_t)c0 * LL + k0n + (lane & 7) * 8);
        stg1 = *(const uint4*)(Vg + (size_t)(c0 + 8) * LL + k0n + (lane & 7) * 8);
      }
    }
    const char* kb = lds + KOFF + p * 5120;
    const char* vb = lds + VOFF + p * 4608;
#pragma unroll
    for (int chunk = 0; chunk < 2; ++chunk) {
      f4 st[2][4];
#pragma unroll
      for (int mt2 = 0; mt2 < 2; ++mt2) {
        h8 kf = *(const h8*)(kb + ((chunk * 2 + mt2) * 16 + ln) * 80 + g * 16);
#pragma unroll
        for (int nt = 0; nt < 4; ++nt) {
          f4 z = {0.f, 0.f, 0.f, 0.f};
          st[mt2][nt] = __builtin_amdgcn_mfma_f32_16x16x32_f16(kf, qf[nt], z, 0, 0, 0);
        }
      }
#pragma unroll
      for (int mt2 = 0; mt2 < 2; ++mt2)
#pragma unroll
        for (int nt = 0; nt < 4; ++nt) {
          float p0 = exp2f(st[mt2][nt][0]);
          float p1 = exp2f(st[mt2][nt][1]);
          float p2 = exp2f(st[mt2][nt][2]);
          float p3 = exp2f(st[mt2][nt][3]);
          lvp[nt] += (p0 + p1) + (p2 + p3);
          unsigned lo = __builtin_bit_cast(unsigned, __builtin_amdgcn_cvt_pkrtz(p0, p1));
          unsigned hi = __builtin_bit_cast(unsigned, __builtin_amdgcn_cvt_pkrtz(p2, p3));
          uint2 pk; pk.x = lo; pk.y = hi;
          *(uint2*)(pw + (nt * 16 + ln) * 72 + mt2 * 32 + g * 8) = pk;
        }
      h8 vf[2];
#pragma unroll
      for (int ct = 0; ct < 2; ++ct)
        vf[ct] = *(const h8*)(vb + (ct * 16 + ln) * 144 + chunk * 64 + g * 16);
#pragma unroll
      for (int nt = 0; nt < 4; ++nt) {
        h4 plo = *(const h4*)(pw + (nt * 16 + ln) * 72 + g * 16);
        h4 phi = *(const h4*)(pw + (nt * 16 + ln) * 72 + g * 16 + 8);
        h8 pf;
        pf[0] = plo[0]; pf[1] = plo[1]; pf[2] = plo[2]; pf[3] = plo[3];
        pf[4] = phi[0]; pf[5] = phi[1]; pf[6] = phi[2]; pf[7] = phi[3];
#pragma unroll
        for (int ct = 0; ct < 2; ++ct)
          o[ct][nt] = __builtin_amdgcn_mfma_f32_16x16x32_f16(vf[ct], pf,
                                                             o[ct][nt], 0, 0, 0);
      }
    }
    if (it < 15) {
      if ((w & 1) == 0) {
        char* kd = lds + KOFF + (1 - p) * 5120;
        *(uint4*)(kd + (h2c * 16 + (lane >> 2)) * 80 + (lane & 3) * 16) = stg0;
        *(uint4*)(kd + ((h2c + 1) * 16 + (lane >> 2)) * 80 + (lane & 3) * 16) = stg1;
      } else {
        char* vd = lds + VOFF + (1 - p) * 4608;
        int c0 = h2c * 8 + (lane >> 3);
        *(uint4*)(vd + c0 * 144 + (lane & 7) * 16) = stg0;
        *(uint4*)(vd + (c0 + 8) * 144 + (lane & 7) * 16) = stg1;
      }
    }
    __syncthreads();
    p ^= 1;
  }

  // ---- epilogue: partial sums + unnormalized partial O (f16)
  _Float16* out = OP + ((size_t)ks * 64 + bh) * (32 * LL);
  float* lsp = LS + ((size_t)ks * 64 + bh) * LL;
#pragma unroll
  for (int nt = 0; nt < 4; ++nt) {
    float s = lvp[nt];
    s += __shfl_xor(s, 16);
    s += __shfl_xor(s, 32);
    int qg = qb * 256 + w * 64 + nt * 16 + ln;
    if (g == 0) lsp[qg] = s;
#pragma unroll
    for (int ct = 0; ct < 2; ++ct)
#pragma unroll
      for (int r = 0; r < 4; ++r)
        out[(size_t)(ct * 16 + g * 4 + r) * LL + qg] = (_Float16)o[ct][nt][r];
  }
}

// -------------------- combine 2 key-segments: AO = (O0+O1)/(l0+l1), f16 out
__global__ __launch_bounds__(256) void k_comb(const _Float16* __restrict__ OP,
    const float* __restrict__ LS, _Float16* __restrict__ AO) {
  int idx = blockIdx.x * 256 + threadIdx.x;    // 64bh*32c*256 lgroups = 524288
  int lg = idx & 255;
  int c  = (idx >> 8) & 31;
  int bh = idx >> 13;
  int l0 = lg * 8;
  const _Float16* o0 = OP + ((size_t)bh * 32 + c) * LL + l0;
  const _Float16* o1 = o0 + (size_t)64 * 32 * LL;
  const float* s0 = LS + (size_t)bh * LL + l0;
  const float* s1 = s0 + (size_t)64 * LL;
  h8 a = *(const h8*)o0;
  h8 b = *(const h8*)o1;
  float4 sa0 = *(const float4*)s0, sa1 = *(const float4*)(s0 + 4);
  float4 sb0 = *(const float4*)s1, sb1 = *(const float4*)(s1 + 4);
  float inv[8];
  inv[0] = 1.f / (sa0.x + sb0.x); inv[1] = 1.f / (sa0.y + sb0.y);
  inv[2] = 1.f / (sa0.z + sb0.z); inv[3] = 1.f / (sa0.w + sb0.w);
  inv[4] = 1.f / (sa1.x + sb1.x); inv[5] = 1.f / (sa1.y + sb1.y);
  inv[6] = 1.f / (sa1.z + sb1.z); inv[7] = 1.f / (sa1.w + sb1.w);
  h8 r;
#pragma unroll
  for (int j = 0; j < 8; ++j)
    r[j] = (_Float16)(((float)a[j] + (float)b[j]) * inv[j]);
  *(h8*)(AO + ((size_t)bh * 32 + c) * LL + l0) = r;
}

// -------- uni GEMM [32,256] f16-in + bias + residual; L-split 16, cc-split 2
__global__ __launch_bounds__(256) void k_uni_res(const _Float16* __restrict__ AO,
    const float* __restrict__ W, const float* __restrict__ bias,
    const float* __restrict__ Xin, float* __restrict__ Y) {
  __shared__ float ps[128 * 17];
  int t    = threadIdx.x;
  int li   = t & 127;
  int cg   = t >> 7;                            // 0..1: channel half
  int bx   = blockIdx.x;                        // 256 blocks
  int lt   = bx & 15;
  int half = (bx >> 4) & 1;
  int b    = bx >> 5;
  int l    = lt * 128 + li;
  const _Float16* ap = AO + (size_t)b * CHH * LL + cg * 128 * (size_t)LL + l;
  float acc[16];
#pragma unroll
  for (int j = 0; j < 16; ++j) acc[j] = 0.f;
  for (int cc = 0; cc < 128; cc += 4) {
    float a0 = (float)ap[(size_t)(cc + 0) * LL];
    float a1 = (float)ap[(size_t)(cc + 1) * LL];
    float a2 = (float)ap[(size_t)(cc + 2) * LL];
    float a3 = (float)ap[(size_t)(cc + 3) * LL];
#pragma unroll
    for (int j = 0; j < 16; ++j) {
      const float* wr = W + (half * 16 + j) * CHH + cg * 128 + cc;
      acc[j] = fmaf(wr[0], a0, acc[j]);
      acc[j] = fmaf(wr[1], a1, acc[j]);
      acc[j] = fmaf(wr[2], a2, acc[j]);
      acc[j] = fmaf(wr[3], a3, acc[j]);
    }
  }
  if (cg) {
#pragma unroll
    for (int j = 0; j < 16; ++j) ps[li * 17 + j] = acc[j];
  }
  __syncthreads();
  if (!cg) {
#pragma unroll
    for (int j = 0; j < 16; ++j) {
      int c = half * 16 + j;
      size_t o = ((size_t)b * CC + c) * LL + l;
      Y[o] = acc[j] + ps[li * 17 + j] + bias[c] + Xin[o];
    }
  }
}

// ---------------------------------------------------------- instance norm
__global__ __launch_bounds__(256) void k_inorm(const float* __restrict__ Y,
    float* __restrict__ X, const float* __restrict__ g,
    const float* __restrict__ bt) {
  __shared__ float red[8];
  int row = blockIdx.x;
  int c = row & 31;
  const float* y = Y + (size_t)row * LL;
  float v[8];
  float s = 0.f, ss = 0.f;
#pragma unroll
  for (int i = 0; i < 8; ++i) {
    v[i] = y[threadIdx.x + 256 * i];
    s += v[i];
    ss = fmaf(v[i], v[i], ss);
  }
#pragma unroll
  for (int off = 32; off; off >>= 1) {
    s  += __shfl_down(s, off);
    ss += __shfl_down(ss, off);
  }
  int wid = threadIdx.x >> 6;
  if ((threadIdx.x & 63) == 0) { red[wid * 2] = s; red[wid * 2 + 1] = ss; }
  __syncthreads();
  if (threadIdx.x == 0) {
    red[0] = red[0] + red[2] + red[4] + red[6];
    red[1] = red[1] + red[3] + red[5] + red[7];
  }
  __syncthreads();
  float mean = red[0] * (1.f / LL);
  float var  = red[1] * (1.f / LL) - mean * mean;
  float rs = rsqrtf(var + 1e-5f) * g[c];
  float bb = bt[c];
#pragma unroll
  for (int i = 0; i < 8; ++i)
    X[(size_t)row * LL + threadIdx.x + 256 * i] = (v[i] - mean) * rs + bb;
}

// -------- fused FFN: relu(W1 x + b1) -> W2 + b2 + residual; 64-l tiles,
// 4 o-groups in-block combined via LDS. grid 256.
__global__ __launch_bounds__(256) void k_ffn(const float* __restrict__ X,
    const float* __restrict__ W1, const float* __restrict__ b1,
    const float* __restrict__ W2, const float* __restrict__ b2,
    float* __restrict__ Y) {
  __shared__ float ps[3][64 * 33];
  int bx = blockIdx.x;                          // 8b * 32lt
  int b = bx >> 5;
  int l0 = (bx & 31) * 64;
  int t = threadIdx.x;
  int li = t & 63;
  int og = t >> 6;                              // 0..3
  int l = l0 + li;
  const float* Xp = X + (size_t)b * CC * LL + l;
  float xv[32];
#pragma unroll
  for (int c = 0; c < 32; ++c) xv[c] = Xp[(size_t)c * LL];
  float acc[32];
#pragma unroll
  for (int c = 0; c < 32; ++c) acc[c] = 0.f;
  for (int o = og * 32; o < og * 32 + 32; ++o) {
    float hs = b1[o];
#pragma unroll
    for (int c = 0; c < 32; ++c) hs = fmaf(W1[o * 32 + c], xv[c], hs);
    hs = fmaxf(hs, 0.f);
#pragma unroll
    for (int c = 0; c < 32; ++c) acc[c] = fmaf(W2[c * 128 + o], hs, acc[c]);
  }
  if (og) {
#pragma unroll
    for (int c = 0; c < 32; ++c) ps[og - 1][li * 33 + c] = acc[c];
  }
  __syncthreads();
  if (!og) {
    float* Yp = Y + (size_t)b * CC * LL + l;
#pragma unroll
    for (int c = 0; c < 32; ++c)
      Yp[(size_t)c * LL] = acc[c] + ps[0][li * 33 + c] + ps[1][li * 33 + c] +
                           ps[2][li * 33 + c] + b2[c] + xv[c];
  }
}

// ------------------------------------------------------------- classifier
__global__ __launch_bounds__(256) void k_cls(const float* __restrict__ X,
    const float* __restrict__ W, const float* __restrict__ bias,
    float* __restrict__ out) {
  int idx = blockIdx.x * 256 + threadIdx.x;
  int l = idx & (LL - 1);
  int b = idx >> 11;
  float s = bias[0];
#pragma unroll
  for (int c = 0; c < CC; ++c)
    s = fmaf(W[c], X[((size_t)b * CC + c) * LL + l], s);
  out[idx] = 1.f / (1.f + __expf(-s));
}

// ------------------------------------------------------------------ launch
extern "C" void kernel_launch(void* const* d_in, const int* in_sizes, int n_in,
                              void* d_out, int out_size, void* d_ws,
                              size_t ws_size, hipStream_t stream) {
  const float* x      = (const float*)d_in[0];
  const float* enc_W  = (const float*)d_in[1];
  const float* enc_b  = (const float*)d_in[2];
  const float* pw_q   = (const float*)d_in[3];
  const float* dw3_q  = (const float*)d_in[4];
  const float* dw15_q = (const float*)d_in[5];
  const float* gate_q = (const float*)d_in[6];
  const float* pw_k   = (const float*)d_in[7];
  const float* dw3_k  = (const float*)d_in[8];
  const float* dw15_k = (const float*)d_in[9];
  const float* gate_k = (const float*)d_in[10];
  const float* pw_v   = (const float*)d_in[11];
  const float* dw3_v  = (const float*)d_in[12];
  const float* dw15_v = (const float*)d_in[13];
  const float* gate_v = (const float*)d_in[14];
  const float* uni_W  = (const float*)d_in[15];
  const float* uni_b  = (const float*)d_in[16];
  const float* n1_g   = (const float*)d_in[17];
  const float* n1_b   = (const float*)d_in[18];
  const float* n2_g   = (const float*)d_in[19];
  const float* n2_b   = (const float*)d_in[20];
  const float* ffn_W1 = (const float*)d_in[21];
  const float* ffn_b1 = (const float*)d_in[22];
  const float* ffn_W2 = (const float*)d_in[23];
  const float* ffn_b2 = (const float*)d_in[24];
  const float* cls_W  = (const float*)d_in[25];
  const float* cls_b  = (const float*)d_in[26];

  float* ws = (float*)d_ws;
  float* X   = ws;                             // [B,32,L] fp32
  float* Y   = ws + 524288;                    // [B,32,L] fp32
  _Float16* AO = (_Float16*)(ws + 1048576);    // [B,256,L] f16 combined attn out
  _Float16* P3 = (_Float16*)(ws + 3145728);    // [3][B,256,L] f16 pw out
  // OP/LS alias P3 (dead once dwt3 consumed it):
  _Float16* OP = (_Float16*)(ws + 3145728);    // [2ks][64bh][32c][L] f16 partials
  float*    LSb = ws + 7340032;                // [2ks][64bh][L] fp32 partial sums
  _Float16* Qt = (_Float16*)(ws + 9437184);    // [64bh][L][32c] f16
  _Float16* Kt = (_Float16*)(ws + 11534336);   // [64bh][L][32c] f16
  _Float16* Vt = (_Float16*)(ws + 13631488);   // [64bh][32c][L] f16

  k_enc<<<2048, 256, 0, stream>>>(x, enc_W, enc_b, X);

  for (int d = 0; d < DD; ++d) {
    k_pw3<<<dim3(2048, 3), 256, 0, stream>>>(X, pw_q + d * CHH * CC,
                                             pw_k + d * CHH * CC,
                                             pw_v + d * CHH * CC, P3);
    k_dwt3<<<dim3(1024, 3), 256, 0, stream>>>(P3,
        dw3_q + d * CHH * 3, dw15_q + d * CHH * 15, gate_q + d * 2,
        dw3_k + d * CHH * 3, dw15_k + d * CHH * 15, gate_k + d * 2,
        dw3_v + d * CHH * 3, dw15_v + d * CHH * 15, gate_v + d * 2,
        Qt, Kt, Vt);
    k_attn<<<dim3(8, 2, 64), 256, 0, stream>>>(Qt, Kt, Vt, OP, LSb);
    k_comb<<<2048, 256, 0, stream>>>(OP, LSb, AO);
    k_uni_res<<<256, 256, 0, stream>>>(AO, uni_W + d * CC * CHH,
                                       uni_b + d * CC, X, Y);
    k_inorm<<<256, 256, 0, stream>>>(Y, X, n1_g + d * CC, n1_b + d * CC);
    k_ffn<<<256, 256, 0, stream>>>(X, ffn_W1 + d * 128 * CC, ffn_b1 + d * 128,
                                   ffn_W2 + d * CC * 128, ffn_b2 + d * CC, Y);
    k_inorm<<<256, 256, 0, stream>>>(Y, X, n2_g + d * CC, n2_b + d * CC);
  }

  k_cls<<<64, 256, 0, stream>>>(X, cls_W, cls_b, (float*)d_out);
}

// Round 10
// 1260.024 us; speedup vs baseline: 1.3326x; 1.1032x over previous
//
#include <hip/hip_runtime.h>
#include <math.h>

#define LL   2048
#define BB   8
#define CC   32
#define CHH  256
#define HH   8
#define DD   6

typedef _Float16 h8 __attribute__((ext_vector_type(8)));
typedef _Float16 h4 __attribute__((ext_vector_type(4)));
typedef float f4 __attribute__((ext_vector_type(4)));

// ---------------------------------------------------------------- encoder
__global__ __launch_bounds__(256) void k_enc(const float* __restrict__ x,
    const float* __restrict__ W, const float* __restrict__ bias,
    float* __restrict__ X) {
  int idx = blockIdx.x * 256 + threadIdx.x;          // B*32*L = 524288
  int l = idx & (LL - 1);
  int c = (idx >> 11) & 31;
  int b = idx >> 16;
  float s = bias[c];
#pragma unroll
  for (int i = 0; i < 6; ++i)
    s = fmaf(W[c * 6 + i], x[((size_t)b * 6 + i) * LL + l], s);
  X[idx] = s;
}

// -------------------------------- pointwise conv, f16 out, z = tensor (q/k/v)
__global__ __launch_bounds__(256) void k_pw3(const float* __restrict__ X,
    const float* __restrict__ Wq, const float* __restrict__ Wk,
    const float* __restrict__ Wv, _Float16* __restrict__ P3) {
  int z  = blockIdx.y;
  int bx = blockIdx.x;
  int t  = threadIdx.x;
  int lt = bx & 7;
  int og = (bx >> 3) & 31;
  int b  = bx >> 8;
  int l  = lt * 256 + t;
  const float* W = (z == 0) ? Wq : (z == 1) ? Wk : Wv;
  const float* Xp = X + (size_t)b * CC * LL + l;
  float acc[8];
#pragma unroll
  for (int j = 0; j < 8; ++j) acc[j] = 0.f;
  for (int c = 0; c < CC; ++c) {
    float xv = Xp[(size_t)c * LL];
#pragma unroll
    for (int j = 0; j < 8; ++j)
      acc[j] = fmaf(W[(og * 8 + j) * CC + c], xv, acc[j]);
  }
  _Float16* op = P3 + (size_t)z * 4194304 + ((size_t)b * CHH + og * 8) * LL + l;
#pragma unroll
  for (int j = 0; j < 8; ++j) op[(size_t)j * LL] = (_Float16)acc[j];
}

// ------------- fused depthwise conv3+conv15+gate+cvt+layout
// in: P3 [z][b][256ch][L] f16. out: z=0 Qt [bh][l][32c] (scaled by C^-.5*log2e),
// z=1 Kt same layout, z=2 Vt [bh][32c][l].
__global__ __launch_bounds__(256) void k_dwt3(const _Float16* __restrict__ P3,
    const float* __restrict__ d3q, const float* __restrict__ d15q, const float* __restrict__ gq,
    const float* __restrict__ d3k, const float* __restrict__ d15k, const float* __restrict__ gk,
    const float* __restrict__ d3v, const float* __restrict__ d15v, const float* __restrict__ gv,
    _Float16* __restrict__ Qt, _Float16* __restrict__ Kt, _Float16* __restrict__ Vt) {
  __shared__ __align__(16) char lds[9728 + 10240];
  int z  = blockIdx.y;
  int bx = blockIdx.x;
  int bh = bx >> 4, lt = bx & 15, l0 = lt * 128;
  int b = bh >> 3, h = bh & 7;
  int t = threadIdx.x;
  const float* w3p  = (z == 0) ? d3q  : (z == 1) ? d3k  : d3v;
  const float* w15p = (z == 0) ? d15q : (z == 1) ? d15k : d15v;
  const float* gp   = (z == 0) ? gq   : (z == 1) ? gk   : gv;

  {
    int row = t >> 3;
    int j0 = (t & 7) * 9;
    const unsigned int* grow = (const unsigned int*)
        (P3 + ((size_t)z * 8 + b) * (CHH * (size_t)LL) + ((size_t)h * 32 + row) * LL + (l0 - 8));
    unsigned int* lrow = (unsigned int*)(lds + row * 304);
#pragma unroll
    for (int k = 0; k < 9; ++k) {
      int j = j0 + k;
      int l = l0 - 8 + 2 * j;
      unsigned int v = 0;
      if (l >= 0 && l < LL) v = grow[j];
      lrow[j] = v;
    }
  }
  __syncthreads();

  int c = t & 31, cg = t >> 5;
  float wv[32];
  {
    const h8* wp = (const h8*)(lds + c * 304 + cg * 32);
#pragma unroll
    for (int q4 = 0; q4 < 4; ++q4) {
      h8 v = wp[q4];
#pragma unroll
      for (int e = 0; e < 8; ++e) wv[q4 * 8 + e] = (float)v[e];
    }
  }
  float r0 = gp[0], r1 = gp[1];
  float mx = fmaxf(r0, r1);
  float e0 = __expf(r0 - mx), e1 = __expf(r1 - mx);
  float gi = 1.f / (e0 + e1);
  float g0 = e0 * gi, g1 = e1 * gi;
  float sc = (z == 0) ? 0.2550765737f : 1.0f;   // C^-0.5 * log2(e) fold
  int ch = h * 32 + c;
  float w3r[3], w15r[15];
#pragma unroll
  for (int k = 0; k < 3; ++k)  w3r[k]  = w3p[ch * 3 + k];
#pragma unroll
  for (int k = 0; k < 15; ++k) w15r[k] = w15p[ch * 15 + k];

  h8 olo, ohi;
#pragma unroll
  for (int i = 0; i < 16; ++i) {
    float a = 0.f;
#pragma unroll
    for (int k = 0; k < 3; ++k) a = fmaf(w3r[k], wv[i + 7 + k], a);
    float s15 = 0.f;
#pragma unroll
    for (int k = 0; k < 15; ++k) s15 = fmaf(w15r[k], wv[i + 1 + k], s15);
    float val = (g0 * a + g1 * s15) * sc;
    if (i < 8) olo[i] = (_Float16)val; else ohi[i - 8] = (_Float16)val;
  }

  if (z == 2) {
    _Float16* dst = Vt + ((size_t)bh * 32 + c) * LL + l0 + cg * 16;
    *(h8*)dst = olo;
    *(h8*)(dst + 8) = ohi;
  } else {
    char* ot = lds + 9728;
#pragma unroll
    for (int i = 0; i < 16; ++i) {
      _Float16 v = (i < 8) ? olo[i] : ohi[i - 8];
      *(_Float16*)(ot + (cg * 16 + i) * 80 + c * 2) = v;
    }
    __syncthreads();
    _Float16* dst = ((z == 0) ? Qt : Kt) + ((size_t)bh * LL + l0) * 32;
    int l = t >> 1, hf = t & 1;
    uint4 a = *(uint4*)(ot + l * 80 + hf * 32);
    uint4 b2 = *(uint4*)(ot + l * 80 + hf * 32 + 16);
    *(uint4*)(dst + (size_t)l * 32 + hf * 16) = a;
    *(uint4*)(dst + (size_t)l * 32 + hf * 16 + 8) = b2;
  }
}

// ------------------------------------------------ MFMA flash attention (f16)
// In-block key-split: 512 thr = 8 waves; waves 0-3 keys [0,1024), waves 4-7
// keys [1024,2048), same 256 q. Single K/V LDS buffer per segment + register
// prefetch (2 barriers/tile). No-max exp2 softmax -> exact in-LDS merge of
// the two segments (fp32), normalize once, f16 out.
// LDS: K seg*5120 @0; V seg*4608 @10240; P w*4608 @19456. Total 55.0 KB.
#define KOFF 0
#define VOFF 10240
#define POFF 19456
__global__ __launch_bounds__(512, 4) void k_attn(
    const _Float16* __restrict__ Qt, const _Float16* __restrict__ Kt,
    const _Float16* __restrict__ Vt, _Float16* __restrict__ AO) {
  __shared__ __align__(16) char lds[56320];
  const int tid  = threadIdx.x;
  const int lane = tid & 63;
  const int w    = tid >> 6;                   // 0..7
  const int seg  = w >> 2;                     // 0..1: key segment
  const int wq   = w & 3;                      // q sub-block within 256
  const int g    = lane >> 4;
  const int ln   = lane & 15;
  const int h2c  = (wq >> 1) * 2;
  const int qb   = blockIdx.x;                 // 0..7
  const int bh   = blockIdx.y;                 // 0..63
  const _Float16* Qg = Qt + ((size_t)bh * LL + qb * 256) * 32;
  const _Float16* Kg = Kt + ((size_t)bh * LL + seg * 1024) * 32;
  const _Float16* Vg = Vt + (size_t)bh * 32 * LL + seg * 1024;

  // Q fragments from global (B operand: [k=c][n=q])
  h8 qf[4];
#pragma unroll
  for (int nt = 0; nt < 4; ++nt)
    qf[nt] = *(const h8*)(Qg + (size_t)(wq * 64 + nt * 16 + ln) * 32 + g * 8);

  char* kb = lds + KOFF + seg * 5120;
  char* vb = lds + VOFF + seg * 4608;
  char* pw = lds + POFF + w * 4608;

  // ---- tile 0 -> regs -> LDS
  uint4 stg0, stg1;
  if ((wq & 1) == 0) {
    const uint4* gk = (const uint4*)Kg;
    stg0 = gk[h2c * 64 + lane];
    stg1 = gk[(h2c + 1) * 64 + lane];
    *(uint4*)(kb + (h2c * 16 + (lane >> 2)) * 80 + (lane & 3) * 16) = stg0;
    *(uint4*)(kb + ((h2c + 1) * 16 + (lane >> 2)) * 80 + (lane & 3) * 16) = stg1;
  } else {
    int c0 = h2c * 8 + (lane >> 3);
    stg0 = *(const uint4*)(Vg + (size_t)c0 * LL + (lane & 7) * 8);
    stg1 = *(const uint4*)(Vg + (size_t)(c0 + 8) * LL + (lane & 7) * 8);
    *(uint4*)(vb + c0 * 144 + (lane & 7) * 16) = stg0;
    *(uint4*)(vb + (c0 + 8) * 144 + (lane & 7) * 16) = stg1;
  }
  __syncthreads();

  f4 o[2][4];
#pragma unroll
  for (int ct = 0; ct < 2; ++ct)
#pragma unroll
    for (int nt = 0; nt < 4; ++nt) o[ct][nt] = (f4){0.f, 0.f, 0.f, 0.f};
  float lvp[4] = {0.f, 0.f, 0.f, 0.f};

  for (int it = 0; it < 16; ++it) {
    if (it < 15) {                             // prefetch next tile to regs
      int k0n = (it + 1) * 64;
      if ((wq & 1) == 0) {
        const uint4* gk = (const uint4*)(Kg + (size_t)k0n * 32);
        stg0 = gk[h2c * 64 + lane];
        stg1 = gk[(h2c + 1) * 64 + lane];
      } else {
        int c0 = h2c * 8 + (lane >> 3);
        stg0 = *(const uint4*)(Vg + (size_t)c0 * LL + k0n + (lane & 7) * 8);
        stg1 = *(const uint4*)(Vg + (size_t)(c0 + 8) * LL + k0n + (lane & 7) * 8);
      }
    }
#pragma unroll
    for (int chunk = 0; chunk < 2; ++chunk) {
      f4 st[2][4];
#pragma unroll
      for (int mt2 = 0; mt2 < 2; ++mt2) {
        h8 kf = *(const h8*)(kb + ((chunk * 2 + mt2) * 16 + ln) * 80 + g * 16);
#pragma unroll
        for (int nt = 0; nt < 4; ++nt) {
          f4 z = {0.f, 0.f, 0.f, 0.f};
          st[mt2][nt] = __builtin_amdgcn_mfma_f32_16x16x32_f16(kf, qf[nt], z, 0, 0, 0);
        }
      }
#pragma unroll
      for (int mt2 = 0; mt2 < 2; ++mt2)
#pragma unroll
        for (int nt = 0; nt < 4; ++nt) {
          float p0 = exp2f(st[mt2][nt][0]);
          float p1 = exp2f(st[mt2][nt][1]);
          float p2 = exp2f(st[mt2][nt][2]);
          float p3 = exp2f(st[mt2][nt][3]);
          lvp[nt] += (p0 + p1) + (p2 + p3);
          unsigned lo = __builtin_bit_cast(unsigned, __builtin_amdgcn_cvt_pkrtz(p0, p1));
          unsigned hi = __builtin_bit_cast(unsigned, __builtin_amdgcn_cvt_pkrtz(p2, p3));
          uint2 pk; pk.x = lo; pk.y = hi;
          *(uint2*)(pw + (nt * 16 + ln) * 72 + mt2 * 32 + g * 8) = pk;
        }
      h8 vf[2];
#pragma unroll
      for (int ct = 0; ct < 2; ++ct)
        vf[ct] = *(const h8*)(vb + (ct * 16 + ln) * 144 + chunk * 64 + g * 16);
#pragma unroll
      for (int nt = 0; nt < 4; ++nt) {
        h4 plo = *(const h4*)(pw + (nt * 16 + ln) * 72 + g * 16);
        h4 phi = *(const h4*)(pw + (nt * 16 + ln) * 72 + g * 16 + 8);
        h8 pf;
        pf[0] = plo[0]; pf[1] = plo[1]; pf[2] = plo[2]; pf[3] = plo[3];
        pf[4] = phi[0]; pf[5] = phi[1]; pf[6] = phi[2]; pf[7] = phi[3];
#pragma unroll
        for (int ct = 0; ct < 2; ++ct)
          o[ct][nt] = __builtin_amdgcn_mfma_f32_16x16x32_f16(vf[ct], pf,
                                                             o[ct][nt], 0, 0, 0);
      }
    }
    __syncthreads();                           // everyone done reading K/V LDS
    if (it < 15) {                             // regs -> LDS (same buffer)
      if ((wq & 1) == 0) {
        *(uint4*)(kb + (h2c * 16 + (lane >> 2)) * 80 + (lane & 3) * 16) = stg0;
        *(uint4*)(kb + ((h2c + 1) * 16 + (lane >> 2)) * 80 + (lane & 3) * 16) = stg1;
      } else {
        int c0 = h2c * 8 + (lane >> 3);
        *(uint4*)(vb + c0 * 144 + (lane & 7) * 16) = stg0;
        *(uint4*)(vb + (c0 + 8) * 144 + (lane & 7) * 16) = stg1;
      }
      __syncthreads();                         // staged
    }
  }

  // ---- reduce partial sums across g (full per-segment sum, all lanes)
  float sred[4];
#pragma unroll
  for (int nt = 0; nt < 4; ++nt) {
    float s = lvp[nt];
    s += __shfl_xor(s, 16);
    s += __shfl_xor(s, 32);
    sred[nt] = s;
  }

  // ---- in-LDS merge: seg1 publishes o (32 f32) + sums (4 f32), lane stride
  //      144 B (2-way banks = free, 16B aligned), region = P space.
  if (seg == 1) {
    char* eo = lds + POFF + wq * 9216 + lane * 144;
#pragma unroll
    for (int nt = 0; nt < 4; ++nt)
#pragma unroll
      for (int ct = 0; ct < 2; ++ct)
        *(f4*)(eo + (nt * 2 + ct) * 16) = o[ct][nt];
    f4 sv; sv[0] = sred[0]; sv[1] = sred[1]; sv[2] = sred[2]; sv[3] = sred[3];
    *(f4*)(eo + 128) = sv;
  }
  __syncthreads();
  if (seg == 0) {
    const char* po = lds + POFF + wq * 9216 + lane * 144;
    f4 s1v = *(const f4*)(po + 128);
    _Float16* out = AO + (size_t)bh * (32 * LL);
#pragma unroll
    for (int nt = 0; nt < 4; ++nt) {
      float inv = 1.f / (sred[nt] + s1v[nt]);
      int qg = qb * 256 + wq * 64 + nt * 16 + ln;
#pragma unroll
      for (int ct = 0; ct < 2; ++ct) {
        f4 o1 = *(const f4*)(po + (nt * 2 + ct) * 16);
#pragma unroll
        for (int r = 0; r < 4; ++r)
          out[(size_t)(ct * 16 + g * 4 + r) * LL + qg] =
              (_Float16)((o[ct][nt][r] + o1[r]) * inv);
      }
    }
  }
}

// -------- uni GEMM [32,256] f16-in + bias + residual; L-split 16, cc-split 2
__global__ __launch_bounds__(256) void k_uni_res(const _Float16* __restrict__ AO,
    const float* __restrict__ W, const float* __restrict__ bias,
    const float* __restrict__ Xin, float* __restrict__ Y) {
  __shared__ float ps[128 * 17];
  int t    = threadIdx.x;
  int li   = t & 127;
  int cg   = t >> 7;                            // 0..1: channel half
  int bx   = blockIdx.x;                        // 256 blocks
  int lt   = bx & 15;
  int half = (bx >> 4) & 1;
  int b    = bx >> 5;
  int l    = lt * 128 + li;
  const _Float16* ap = AO + (size_t)b * CHH * LL + cg * 128 * (size_t)LL + l;
  float acc[16];
#pragma unroll
  for (int j = 0; j < 16; ++j) acc[j] = 0.f;
  for (int cc = 0; cc < 128; cc += 4) {
    float a0 = (float)ap[(size_t)(cc + 0) * LL];
    float a1 = (float)ap[(size_t)(cc + 1) * LL];
    float a2 = (float)ap[(size_t)(cc + 2) * LL];
    float a3 = (float)ap[(size_t)(cc + 3) * LL];
#pragma unroll
    for (int j = 0; j < 16; ++j) {
      const float* wr = W + (half * 16 + j) * CHH + cg * 128 + cc;
      acc[j] = fmaf(wr[0], a0, acc[j]);
      acc[j] = fmaf(wr[1], a1, acc[j]);
      acc[j] = fmaf(wr[2], a2, acc[j]);
      acc[j] = fmaf(wr[3], a3, acc[j]);
    }
  }
  if (cg) {
#pragma unroll
    for (int j = 0; j < 16; ++j) ps[li * 17 + j] = acc[j];
  }
  __syncthreads();
  if (!cg) {
#pragma unroll
    for (int j = 0; j < 16; ++j) {
      int c = half * 16 + j;
      size_t o = ((size_t)b * CC + c) * LL + l;
      Y[o] = acc[j] + ps[li * 17 + j] + bias[c] + Xin[o];
    }
  }
}

// ---------------------------------------------------------- instance norm
__global__ __launch_bounds__(256) void k_inorm(const float* __restrict__ Y,
    float* __restrict__ X, const float* __restrict__ g,
    const float* __restrict__ bt) {
  __shared__ float red[8];
  int row = blockIdx.x;
  int c = row & 31;
  const float* y = Y + (size_t)row * LL;
  float v[8];
  float s = 0.f, ss = 0.f;
#pragma unroll
  for (int i = 0; i < 8; ++i) {
    v[i] = y[threadIdx.x + 256 * i];
    s += v[i];
    ss = fmaf(v[i], v[i], ss);
  }
#pragma unroll
  for (int off = 32; off; off >>= 1) {
    s  += __shfl_down(s, off);
    ss += __shfl_down(ss, off);
  }
  int wid = threadIdx.x >> 6;
  if ((threadIdx.x & 63) == 0) { red[wid * 2] = s; red[wid * 2 + 1] = ss; }
  __syncthreads();
  if (threadIdx.x == 0) {
    red[0] = red[0] + red[2] + red[4] + red[6];
    red[1] = red[1] + red[3] + red[5] + red[7];
  }
  __syncthreads();
  float mean = red[0] * (1.f / LL);
  float var  = red[1] * (1.f / LL) - mean * mean;
  float rs = rsqrtf(var + 1e-5f) * g[c];
  float bb = bt[c];
#pragma unroll
  for (int i = 0; i < 8; ++i)
    X[(size_t)row * LL + threadIdx.x + 256 * i] = (v[i] - mean) * rs + bb;
}

// -------- fused FFN: relu(W1 x + b1) -> W2 + b2 + residual; 64-l tiles,
// 4 o-groups in-block combined via LDS. grid 256.
__global__ __launch_bounds__(256) void k_ffn(const float* __restrict__ X,
    const float* __restrict__ W1, const float* __restrict__ b1,
    const float* __restrict__ W2, const float* __restrict__ b2,
    float* __restrict__ Y) {
  __shared__ float ps[3][64 * 33];
  int bx = blockIdx.x;                          // 8b * 32lt
  int b = bx >> 5;
  int l0 = (bx & 31) * 64;
  int t = threadIdx.x;
  int li = t & 63;
  int og = t >> 6;                              // 0..3
  int l = l0 + li;
  const float* Xp = X + (size_t)b * CC * LL + l;
  float xv[32];
#pragma unroll
  for (int c = 0; c < 32; ++c) xv[c] = Xp[(size_t)c * LL];
  float acc[32];
#pragma unroll
  for (int c = 0; c < 32; ++c) acc[c] = 0.f;
  for (int o = og * 32; o < og * 32 + 32; ++o) {
    float hs = b1[o];
#pragma unroll
    for (int c = 0; c < 32; ++c) hs = fmaf(W1[o * 32 + c], xv[c], hs);
    hs = fmaxf(hs, 0.f);
#pragma unroll
    for (int c = 0; c < 32; ++c) acc[c] = fmaf(W2[c * 128 + o], hs, acc[c]);
  }
  if (og) {
#pragma unroll
    for (int c = 0; c < 32; ++c) ps[og - 1][li * 33 + c] = acc[c];
  }
  __syncthreads();
  if (!og) {
    float* Yp = Y + (size_t)b * CC * LL + l;
#pragma unroll
    for (int c = 0; c < 32; ++c)
      Yp[(size_t)c * LL] = acc[c] + ps[0][li * 33 + c] + ps[1][li * 33 + c] +
                           ps[2][li * 33 + c] + b2[c] + xv[c];
  }
}

// ------------------------------------------------------------- classifier
__global__ __launch_bounds__(256) void k_cls(const float* __restrict__ X,
    const float* __restrict__ W, const float* __restrict__ bias,
    float* __restrict__ out) {
  int idx = blockIdx.x * 256 + threadIdx.x;
  int l = idx & (LL - 1);
  int b = idx >> 11;
  float s = bias[0];
#pragma unroll
  for (int c = 0; c < CC; ++c)
    s = fmaf(W[c], X[((size_t)b * CC + c) * LL + l], s);
  out[idx] = 1.f / (1.f + __expf(-s));
}

// ------------------------------------------------------------------ launch
extern "C" void kernel_launch(void* const* d_in, const int* in_sizes, int n_in,
                              void* d_out, int out_size, void* d_ws,
                              size_t ws_size, hipStream_t stream) {
  const float* x      = (const float*)d_in[0];
  const float* enc_W  = (const float*)d_in[1];
  const float* enc_b  = (const float*)d_in[2];
  const float* pw_q   = (const float*)d_in[3];
  const float* dw3_q  = (const float*)d_in[4];
  const float* dw15_q = (const float*)d_in[5];
  const float* gate_q = (const float*)d_in[6];
  const float* pw_k   = (const float*)d_in[7];
  const float* dw3_k  = (const float*)d_in[8];
  const float* dw15_k = (const float*)d_in[9];
  const float* gate_k = (const float*)d_in[10];
  const float* pw_v   = (const float*)d_in[11];
  const float* dw3_v  = (const float*)d_in[12];
  const float* dw15_v = (const float*)d_in[13];
  const float* gate_v = (const float*)d_in[14];
  const float* uni_W  = (const float*)d_in[15];
  const float* uni_b  = (const float*)d_in[16];
  const float* n1_g   = (const float*)d_in[17];
  const float* n1_b   = (const float*)d_in[18];
  const float* n2_g   = (const float*)d_in[19];
  const float* n2_b   = (const float*)d_in[20];
  const float* ffn_W1 = (const float*)d_in[21];
  const float* ffn_b1 = (const float*)d_in[22];
  const float* ffn_W2 = (const float*)d_in[23];
  const float* ffn_b2 = (const float*)d_in[24];
  const float* cls_W  = (const float*)d_in[25];
  const float* cls_b  = (const float*)d_in[26];

  float* ws = (float*)d_ws;
  float* X   = ws;                             // [B,32,L] fp32
  float* Y   = ws + 524288;                    // [B,32,L] fp32
  _Float16* AO = (_Float16*)(ws + 1048576);    // [B,256,L] f16 attn out
  _Float16* P3 = (_Float16*)(ws + 3145728);    // [3][B,256,L] f16 pw out
  _Float16* Qt = (_Float16*)(ws + 9437184);    // [64bh][L][32c] f16
  _Float16* Kt = (_Float16*)(ws + 11534336);   // [64bh][L][32c] f16
  _Float16* Vt = (_Float16*)(ws + 13631488);   // [64bh][32c][L] f16

  k_enc<<<2048, 256, 0, stream>>>(x, enc_W, enc_b, X);

  for (int d = 0; d < DD; ++d) {
    k_pw3<<<dim3(2048, 3), 256, 0, stream>>>(X, pw_q + d * CHH * CC,
                                             pw_k + d * CHH * CC,
                                             pw_v + d * CHH * CC, P3);
    k_dwt3<<<dim3(1024, 3), 256, 0, stream>>>(P3,
        dw3_q + d * CHH * 3, dw15_q + d * CHH * 15, gate_q + d * 2,
        dw3_k + d * CHH * 3, dw15_k + d * CHH * 15, gate_k + d * 2,
        dw3_v + d * CHH * 3, dw15_v + d * CHH * 15, gate_v + d * 2,
        Qt, Kt, Vt);
    k_attn<<<dim3(8, 64), 512, 0, stream>>>(Qt, Kt, Vt, AO);
    k_uni_res<<<256, 256, 0, stream>>>(AO, uni_W + d * CC * CHH,
                                       uni_b + d * CC, X, Y);
    k_inorm<<<256, 256, 0, stream>>>(Y, X, n1_g + d * CC, n1_b + d * CC);
    k_ffn<<<256, 256, 0, stream>>>(X, ffn_W1 + d * 128 * CC, ffn_b1 + d * 128,
                                   ffn_W2 + d * CC * 128, ffn_b2 + d * CC, Y);
    k_inorm<<<256, 256, 0, stream>>>(Y, X, n2_g + d * CC, n2_b + d * CC);
  }

  k_cls<<<64, 256, 0, stream>>>(X, cls_W, cls_b, (float*)d_out);
}

// Round 11
// 1217.336 us; speedup vs baseline: 1.3793x; 1.0351x over previous
//
#include <hip/hip_runtime.h>
#include <math.h>

#define LL   2048
#define BB   8
#define CC   32
#define CHH  256
#define HH   8
#define DD   6

typedef _Float16 h8 __attribute__((ext_vector_type(8)));
typedef _Float16 h4 __attribute__((ext_vector_type(4)));
typedef float f4 __attribute__((ext_vector_type(4)));

// ---------------------------------------------------------------- encoder
__global__ __launch_bounds__(256) void k_enc(const float* __restrict__ x,
    const float* __restrict__ W, const float* __restrict__ bias,
    float* __restrict__ X) {
  int idx = blockIdx.x * 256 + threadIdx.x;          // B*32*L = 524288
  int l = idx & (LL - 1);
  int c = (idx >> 11) & 31;
  int b = idx >> 16;
  float s = bias[c];
#pragma unroll
  for (int i = 0; i < 6; ++i)
    s = fmaf(W[c * 6 + i], x[((size_t)b * 6 + i) * LL + l], s);
  X[idx] = s;
}

// -------------------------------- pointwise conv, f16 out, z = tensor (q/k/v)
__global__ __launch_bounds__(256) void k_pw3(const float* __restrict__ X,
    const float* __restrict__ Wq, const float* __restrict__ Wk,
    const float* __restrict__ Wv, _Float16* __restrict__ P3) {
  int z  = blockIdx.y;
  int bx = blockIdx.x;
  int t  = threadIdx.x;
  int lt = bx & 7;
  int og = (bx >> 3) & 31;
  int b  = bx >> 8;
  int l  = lt * 256 + t;
  const float* W = (z == 0) ? Wq : (z == 1) ? Wk : Wv;
  const float* Xp = X + (size_t)b * CC * LL + l;
  float acc[8];
#pragma unroll
  for (int j = 0; j < 8; ++j) acc[j] = 0.f;
  for (int c = 0; c < CC; ++c) {
    float xv = Xp[(size_t)c * LL];
#pragma unroll
    for (int j = 0; j < 8; ++j)
      acc[j] = fmaf(W[(og * 8 + j) * CC + c], xv, acc[j]);
  }
  _Float16* op = P3 + (size_t)z * 4194304 + ((size_t)b * CHH + og * 8) * LL + l;
#pragma unroll
  for (int j = 0; j < 8; ++j) op[(size_t)j * LL] = (_Float16)acc[j];
}

// ------------- fused depthwise conv3+conv15+gate+cvt+layout
// in: P3 [z][b][256ch][L] f16. out: z=0 Qt [bh][l][32c] (scaled by C^-.5*log2e),
// z=1 Kt same layout, z=2 Vt [bh][32c][l].
__global__ __launch_bounds__(256) void k_dwt3(const _Float16* __restrict__ P3,
    const float* __restrict__ d3q, const float* __restrict__ d15q, const float* __restrict__ gq,
    const float* __restrict__ d3k, const float* __restrict__ d15k, const float* __restrict__ gk,
    const float* __restrict__ d3v, const float* __restrict__ d15v, const float* __restrict__ gv,
    _Float16* __restrict__ Qt, _Float16* __restrict__ Kt, _Float16* __restrict__ Vt) {
  __shared__ __align__(16) char lds[9728 + 10240];
  int z  = blockIdx.y;
  int bx = blockIdx.x;
  int bh = bx >> 4, lt = bx & 15, l0 = lt * 128;
  int b = bh >> 3, h = bh & 7;
  int t = threadIdx.x;
  const float* w3p  = (z == 0) ? d3q  : (z == 1) ? d3k  : d3v;
  const float* w15p = (z == 0) ? d15q : (z == 1) ? d15k : d15v;
  const float* gp   = (z == 0) ? gq   : (z == 1) ? gk   : gv;

  {
    int row = t >> 3;
    int j0 = (t & 7) * 9;
    const unsigned int* grow = (const unsigned int*)
        (P3 + ((size_t)z * 8 + b) * (CHH * (size_t)LL) + ((size_t)h * 32 + row) * LL + (l0 - 8));
    unsigned int* lrow = (unsigned int*)(lds + row * 304);
#pragma unroll
    for (int k = 0; k < 9; ++k) {
      int j = j0 + k;
      int l = l0 - 8 + 2 * j;
      unsigned int v = 0;
      if (l >= 0 && l < LL) v = grow[j];
      lrow[j] = v;
    }
  }
  __syncthreads();

  int c = t & 31, cg = t >> 5;
  float wv[32];
  {
    const h8* wp = (const h8*)(lds + c * 304 + cg * 32);
#pragma unroll
    for (int q4 = 0; q4 < 4; ++q4) {
      h8 v = wp[q4];
#pragma unroll
      for (int e = 0; e < 8; ++e) wv[q4 * 8 + e] = (float)v[e];
    }
  }
  float r0 = gp[0], r1 = gp[1];
  float mx = fmaxf(r0, r1);
  float e0 = __expf(r0 - mx), e1 = __expf(r1 - mx);
  float gi = 1.f / (e0 + e1);
  float g0 = e0 * gi, g1 = e1 * gi;
  float sc = (z == 0) ? 0.2550765737f : 1.0f;   // C^-0.5 * log2(e) fold
  int ch = h * 32 + c;
  float w3r[3], w15r[15];
#pragma unroll
  for (int k = 0; k < 3; ++k)  w3r[k]  = w3p[ch * 3 + k];
#pragma unroll
  for (int k = 0; k < 15; ++k) w15r[k] = w15p[ch * 15 + k];

  h8 olo, ohi;
#pragma unroll
  for (int i = 0; i < 16; ++i) {
    float a = 0.f;
#pragma unroll
    for (int k = 0; k < 3; ++k) a = fmaf(w3r[k], wv[i + 7 + k], a);
    float s15 = 0.f;
#pragma unroll
    for (int k = 0; k < 15; ++k) s15 = fmaf(w15r[k], wv[i + 1 + k], s15);
    float val = (g0 * a + g1 * s15) * sc;
    if (i < 8) olo[i] = (_Float16)val; else ohi[i - 8] = (_Float16)val;
  }

  if (z == 2) {
    _Float16* dst = Vt + ((size_t)bh * 32 + c) * LL + l0 + cg * 16;
    *(h8*)dst = olo;
    *(h8*)(dst + 8) = ohi;
  } else {
    char* ot = lds + 9728;
#pragma unroll
    for (int i = 0; i < 16; ++i) {
      _Float16 v = (i < 8) ? olo[i] : ohi[i - 8];
      *(_Float16*)(ot + (cg * 16 + i) * 80 + c * 2) = v;
    }
    __syncthreads();
    _Float16* dst = ((z == 0) ? Qt : Kt) + ((size_t)bh * LL + l0) * 32;
    int l = t >> 1, hf = t & 1;
    uint4 a = *(uint4*)(ot + l * 80 + hf * 32);
    uint4 b2 = *(uint4*)(ot + l * 80 + hf * 32 + 16);
    *(uint4*)(dst + (size_t)l * 32 + hf * 16) = a;
    *(uint4*)(dst + (size_t)l * 32 + hf * 16 + 8) = b2;
  }
}

// ------------------------------------------------ MFMA flash attention (f16)
// In-block key-split: 512 thr = 8 waves; waves 0-3 keys [0,1024), waves 4-7
// keys [1024,2048), same 256 q. Single K/V LDS buffer per segment + register
// prefetch (2 barriers/tile). No-max exp2 softmax -> exact in-LDS merge of
// the two segments (fp32), normalize once, f16 out.
// LDS: K seg*5120 @0; V seg*4608 @10240; P w*4608 @19456. Total 55.0 KB.
// launch_bounds(512,2): min-waves 4 squeezed VGPR to 64 and spilled ~67MB/
// dispatch to scratch (R10 counters); cap 256 lets allocator fit ~105 live
// floats under 128 -> still 2 blocks/CU, zero spill.
#define KOFF 0
#define VOFF 10240
#define POFF 19456
__global__ __launch_bounds__(512, 2) void k_attn(
    const _Float16* __restrict__ Qt, const _Float16* __restrict__ Kt,
    const _Float16* __restrict__ Vt, _Float16* __restrict__ AO) {
  __shared__ __align__(16) char lds[56320];
  const int tid  = threadIdx.x;
  const int lane = tid & 63;
  const int w    = tid >> 6;                   // 0..7
  const int seg  = w >> 2;                     // 0..1: key segment
  const int wq   = w & 3;                      // q sub-block within 256
  const int g    = lane >> 4;
  const int ln   = lane & 15;
  const int h2c  = (wq >> 1) * 2;
  const int qb   = blockIdx.x;                 // 0..7
  const int bh   = blockIdx.y;                 // 0..63
  const _Float16* Qg = Qt + ((size_t)bh * LL + qb * 256) * 32;
  const _Float16* Kg = Kt + ((size_t)bh * LL + seg * 1024) * 32;
  const _Float16* Vg = Vt + (size_t)bh * 32 * LL + seg * 1024;

  // Q fragments from global (B operand: [k=c][n=q])
  h8 qf[4];
#pragma unroll
  for (int nt = 0; nt < 4; ++nt)
    qf[nt] = *(const h8*)(Qg + (size_t)(wq * 64 + nt * 16 + ln) * 32 + g * 8);

  char* kb = lds + KOFF + seg * 5120;
  char* vb = lds + VOFF + seg * 4608;
  char* pw = lds + POFF + w * 4608;

  // ---- tile 0 -> regs -> LDS
  uint4 stg0, stg1;
  if ((wq & 1) == 0) {
    const uint4* gk = (const uint4*)Kg;
    stg0 = gk[h2c * 64 + lane];
    stg1 = gk[(h2c + 1) * 64 + lane];
    *(uint4*)(kb + (h2c * 16 + (lane >> 2)) * 80 + (lane & 3) * 16) = stg0;
    *(uint4*)(kb + ((h2c + 1) * 16 + (lane >> 2)) * 80 + (lane & 3) * 16) = stg1;
  } else {
    int c0 = h2c * 8 + (lane >> 3);
    stg0 = *(const uint4*)(Vg + (size_t)c0 * LL + (lane & 7) * 8);
    stg1 = *(const uint4*)(Vg + (size_t)(c0 + 8) * LL + (lane & 7) * 8);
    *(uint4*)(vb + c0 * 144 + (lane & 7) * 16) = stg0;
    *(uint4*)(vb + (c0 + 8) * 144 + (lane & 7) * 16) = stg1;
  }
  __syncthreads();

  f4 o[2][4];
#pragma unroll
  for (int ct = 0; ct < 2; ++ct)
#pragma unroll
    for (int nt = 0; nt < 4; ++nt) o[ct][nt] = (f4){0.f, 0.f, 0.f, 0.f};
  float lvp[4] = {0.f, 0.f, 0.f, 0.f};

  for (int it = 0; it < 16; ++it) {
    if (it < 15) {                             // prefetch next tile to regs
      int k0n = (it + 1) * 64;
      if ((wq & 1) == 0) {
        const uint4* gk = (const uint4*)(Kg + (size_t)k0n * 32);
        stg0 = gk[h2c * 64 + lane];
        stg1 = gk[(h2c + 1) * 64 + lane];
      } else {
        int c0 = h2c * 8 + (lane >> 3);
        stg0 = *(const uint4*)(Vg + (size_t)c0 * LL + k0n + (lane & 7) * 8);
        stg1 = *(const uint4*)(Vg + (size_t)(c0 + 8) * LL + k0n + (lane & 7) * 8);
      }
    }
#pragma unroll
    for (int chunk = 0; chunk < 2; ++chunk) {
      f4 st[2][4];
#pragma unroll
      for (int mt2 = 0; mt2 < 2; ++mt2) {
        h8 kf = *(const h8*)(kb + ((chunk * 2 + mt2) * 16 + ln) * 80 + g * 16);
#pragma unroll
        for (int nt = 0; nt < 4; ++nt) {
          f4 z = {0.f, 0.f, 0.f, 0.f};
          st[mt2][nt] = __builtin_amdgcn_mfma_f32_16x16x32_f16(kf, qf[nt], z, 0, 0, 0);
        }
      }
#pragma unroll
      for (int mt2 = 0; mt2 < 2; ++mt2)
#pragma unroll
        for (int nt = 0; nt < 4; ++nt) {
          float p0 = exp2f(st[mt2][nt][0]);
          float p1 = exp2f(st[mt2][nt][1]);
          float p2 = exp2f(st[mt2][nt][2]);
          float p3 = exp2f(st[mt2][nt][3]);
          lvp[nt] += (p0 + p1) + (p2 + p3);
          unsigned lo = __builtin_bit_cast(unsigned, __builtin_amdgcn_cvt_pkrtz(p0, p1));
          unsigned hi = __builtin_bit_cast(unsigned, __builtin_amdgcn_cvt_pkrtz(p2, p3));
          uint2 pk; pk.x = lo; pk.y = hi;
          *(uint2*)(pw + (nt * 16 + ln) * 72 + mt2 * 32 + g * 8) = pk;
        }
      h8 vf[2];
#pragma unroll
      for (int ct = 0; ct < 2; ++ct)
        vf[ct] = *(const h8*)(vb + (ct * 16 + ln) * 144 + chunk * 64 + g * 16);
#pragma unroll
      for (int nt = 0; nt < 4; ++nt) {
        h4 plo = *(const h4*)(pw + (nt * 16 + ln) * 72 + g * 16);
        h4 phi = *(const h4*)(pw + (nt * 16 + ln) * 72 + g * 16 + 8);
        h8 pf;
        pf[0] = plo[0]; pf[1] = plo[1]; pf[2] = plo[2]; pf[3] = plo[3];
        pf[4] = phi[0]; pf[5] = phi[1]; pf[6] = phi[2]; pf[7] = phi[3];
#pragma unroll
        for (int ct = 0; ct < 2; ++ct)
          o[ct][nt] = __builtin_amdgcn_mfma_f32_16x16x32_f16(vf[ct], pf,
                                                             o[ct][nt], 0, 0, 0);
      }
    }
    __syncthreads();                           // everyone done reading K/V LDS
    if (it < 15) {                             // regs -> LDS (same buffer)
      if ((wq & 1) == 0) {
        *(uint4*)(kb + (h2c * 16 + (lane >> 2)) * 80 + (lane & 3) * 16) = stg0;
        *(uint4*)(kb + ((h2c + 1) * 16 + (lane >> 2)) * 80 + (lane & 3) * 16) = stg1;
      } else {
        int c0 = h2c * 8 + (lane >> 3);
        *(uint4*)(vb + c0 * 144 + (lane & 7) * 16) = stg0;
        *(uint4*)(vb + (c0 + 8) * 144 + (lane & 7) * 16) = stg1;
      }
      __syncthreads();                         // staged
    }
  }

  // ---- reduce partial sums across g (full per-segment sum, all lanes)
  float sred[4];
#pragma unroll
  for (int nt = 0; nt < 4; ++nt) {
    float s = lvp[nt];
    s += __shfl_xor(s, 16);
    s += __shfl_xor(s, 32);
    sred[nt] = s;
  }

  // ---- in-LDS merge: seg1 publishes o (32 f32) + sums (4 f32), lane stride
  //      144 B (2-way banks = free, 16B aligned), region = P space.
  if (seg == 1) {
    char* eo = lds + POFF + wq * 9216 + lane * 144;
#pragma unroll
    for (int nt = 0; nt < 4; ++nt)
#pragma unroll
      for (int ct = 0; ct < 2; ++ct)
        *(f4*)(eo + (nt * 2 + ct) * 16) = o[ct][nt];
    f4 sv; sv[0] = sred[0]; sv[1] = sred[1]; sv[2] = sred[2]; sv[3] = sred[3];
    *(f4*)(eo + 128) = sv;
  }
  __syncthreads();
  if (seg == 0) {
    const char* po = lds + POFF + wq * 9216 + lane * 144;
    f4 s1v = *(const f4*)(po + 128);
    _Float16* out = AO + (size_t)bh * (32 * LL);
#pragma unroll
    for (int nt = 0; nt < 4; ++nt) {
      float inv = 1.f / (sred[nt] + s1v[nt]);
      int qg = qb * 256 + wq * 64 + nt * 16 + ln;
#pragma unroll
      for (int ct = 0; ct < 2; ++ct) {
        f4 o1 = *(const f4*)(po + (nt * 2 + ct) * 16);
#pragma unroll
        for (int r = 0; r < 4; ++r)
          out[(size_t)(ct * 16 + g * 4 + r) * LL + qg] =
              (_Float16)((o[ct][nt][r] + o1[r]) * inv);
      }
    }
  }
}

// -------- uni GEMM [32,256] f16-in + bias + residual; L-split 16, cc-split 2
__global__ __launch_bounds__(256) void k_uni_res(const _Float16* __restrict__ AO,
    const float* __restrict__ W, const float* __restrict__ bias,
    const float* __restrict__ Xin, float* __restrict__ Y) {
  __shared__ float ps[128 * 17];
  int t    = threadIdx.x;
  int li   = t & 127;
  int cg   = t >> 7;                            // 0..1: channel half
  int bx   = blockIdx.x;                        // 256 blocks
  int lt   = bx & 15;
  int half = (bx >> 4) & 1;
  int b    = bx >> 5;
  int l    = lt * 128 + li;
  const _Float16* ap = AO + (size_t)b * CHH * LL + cg * 128 * (size_t)LL + l;
  float acc[16];
#pragma unroll
  for (int j = 0; j < 16; ++j) acc[j] = 0.f;
  for (int cc = 0; cc < 128; cc += 4) {
    float a0 = (float)ap[(size_t)(cc + 0) * LL];
    float a1 = (float)ap[(size_t)(cc + 1) * LL];
    float a2 = (float)ap[(size_t)(cc + 2) * LL];
    float a3 = (float)ap[(size_t)(cc + 3) * LL];
#pragma unroll
    for (int j = 0; j < 16; ++j) {
      const float* wr = W + (half * 16 + j) * CHH + cg * 128 + cc;
      acc[j] = fmaf(wr[0], a0, acc[j]);
      acc[j] = fmaf(wr[1], a1, acc[j]);
      acc[j] = fmaf(wr[2], a2, acc[j]);
      acc[j] = fmaf(wr[3], a3, acc[j]);
    }
  }
  if (cg) {
#pragma unroll
    for (int j = 0; j < 16; ++j) ps[li * 17 + j] = acc[j];
  }
  __syncthreads();
  if (!cg) {
#pragma unroll
    for (int j = 0; j < 16; ++j) {
      int c = half * 16 + j;
      size_t o = ((size_t)b * CC + c) * LL + l;
      Y[o] = acc[j] + ps[li * 17 + j] + bias[c] + Xin[o];
    }
  }
}

// ---------------------------------------------------------- instance norm
__global__ __launch_bounds__(256) void k_inorm(const float* __restrict__ Y,
    float* __restrict__ X, const float* __restrict__ g,
    const float* __restrict__ bt) {
  __shared__ float red[8];
  int row = blockIdx.x;
  int c = row & 31;
  const float* y = Y + (size_t)row * LL;
  float v[8];
  float s = 0.f, ss = 0.f;
#pragma unroll
  for (int i = 0; i < 8; ++i) {
    v[i] = y[threadIdx.x + 256 * i];
    s += v[i];
    ss = fmaf(v[i], v[i], ss);
  }
#pragma unroll
  for (int off = 32; off; off >>= 1) {
    s  += __shfl_down(s, off);
    ss += __shfl_down(ss, off);
  }
  int wid = threadIdx.x >> 6;
  if ((threadIdx.x & 63) == 0) { red[wid * 2] = s; red[wid * 2 + 1] = ss; }
  __syncthreads();
  if (threadIdx.x == 0) {
    red[0] = red[0] + red[2] + red[4] + red[6];
    red[1] = red[1] + red[3] + red[5] + red[7];
  }
  __syncthreads();
  float mean = red[0] * (1.f / LL);
  float var  = red[1] * (1.f / LL) - mean * mean;
  float rs = rsqrtf(var + 1e-5f) * g[c];
  float bb = bt[c];
#pragma unroll
  for (int i = 0; i < 8; ++i)
    X[(size_t)row * LL + threadIdx.x + 256 * i] = (v[i] - mean) * rs + bb;
}

// -------- fused FFN: relu(W1 x + b1) -> W2 + b2 + residual; 64-l tiles,
// 4 o-groups in-block combined via LDS. grid 256.
__global__ __launch_bounds__(256) void k_ffn(const float* __restrict__ X,
    const float* __restrict__ W1, const float* __restrict__ b1,
    const float* __restrict__ W2, const float* __restrict__ b2,
    float* __restrict__ Y) {
  __shared__ float ps[3][64 * 33];
  int bx = blockIdx.x;                          // 8b * 32lt
  int b = bx >> 5;
  int l0 = (bx & 31) * 64;
  int t = threadIdx.x;
  int li = t & 63;
  int og = t >> 6;                              // 0..3
  int l = l0 + li;
  const float* Xp = X + (size_t)b * CC * LL + l;
  float xv[32];
#pragma unroll
  for (int c = 0; c < 32; ++c) xv[c] = Xp[(size_t)c * LL];
  float acc[32];
#pragma unroll
  for (int c = 0; c < 32; ++c) acc[c] = 0.f;
  for (int o = og * 32; o < og * 32 + 32; ++o) {
    float hs = b1[o];
#pragma unroll
    for (int c = 0; c < 32; ++c) hs = fmaf(W1[o * 32 + c], xv[c], hs);
    hs = fmaxf(hs, 0.f);
#pragma unroll
    for (int c = 0; c < 32; ++c) acc[c] = fmaf(W2[c * 128 + o], hs, acc[c]);
  }
  if (og) {
#pragma unroll
    for (int c = 0; c < 32; ++c) ps[og - 1][li * 33 + c] = acc[c];
  }
  __syncthreads();
  if (!og) {
    float* Yp = Y + (size_t)b * CC * LL + l;
#pragma unroll
    for (int c = 0; c < 32; ++c)
      Yp[(size_t)c * LL] = acc[c] + ps[0][li * 33 + c] + ps[1][li * 33 + c] +
                           ps[2][li * 33 + c] + b2[c] + xv[c];
  }
}

// ------------------------------------------------------------- classifier
__global__ __launch_bounds__(256) void k_cls(const float* __restrict__ X,
    const float* __restrict__ W, const float* __restrict__ bias,
    float* __restrict__ out) {
  int idx = blockIdx.x * 256 + threadIdx.x;
  int l = idx & (LL - 1);
  int b = idx >> 11;
  float s = bias[0];
#pragma unroll
  for (int c = 0; c < CC; ++c)
    s = fmaf(W[c], X[((size_t)b * CC + c) * LL + l], s);
  out[idx] = 1.f / (1.f + __expf(-s));
}

// ------------------------------------------------------------------ launch
extern "C" void kernel_launch(void* const* d_in, const int* in_sizes, int n_in,
                              void* d_out, int out_size, void* d_ws,
                              size_t ws_size, hipStream_t stream) {
  const float* x      = (const float*)d_in[0];
  const float* enc_W  = (const float*)d_in[1];
  const float* enc_b  = (const float*)d_in[2];
  const float* pw_q   = (const float*)d_in[3];
  const float* dw3_q  = (const float*)d_in[4];
  const float* dw15_q = (const float*)d_in[5];
  const float* gate_q = (const float*)d_in[6];
  const float* pw_k   = (const float*)d_in[7];
  const float* dw3_k  = (const float*)d_in[8];
  const float* dw15_k = (const float*)d_in[9];
  const float* gate_k = (const float*)d_in[10];
  const float* pw_v   = (const float*)d_in[11];
  const float* dw3_v  = (const float*)d_in[12];
  const float* dw15_v = (const float*)d_in[13];
  const float* gate_v = (const float*)d_in[14];
  const float* uni_W  = (const float*)d_in[15];
  const float* uni_b  = (const float*)d_in[16];
  const float* n1_g   = (const float*)d_in[17];
  const float* n1_b   = (const float*)d_in[18];
  const float* n2_g   = (const float*)d_in[19];
  const float* n2_b   = (const float*)d_in[20];
  const float* ffn_W1 = (const float*)d_in[21];
  const float* ffn_b1 = (const float*)d_in[22];
  const float* ffn_W2 = (const float*)d_in[23];
  const float* ffn_b2 = (const float*)d_in[24];
  const float* cls_W  = (const float*)d_in[25];
  const float* cls_b  = (const float*)d_in[26];

  float* ws = (float*)d_ws;
  float* X   = ws;                             // [B,32,L] fp32
  float* Y   = ws + 524288;                    // [B,32,L] fp32
  _Float16* AO = (_Float16*)(ws + 1048576);    // [B,256,L] f16 attn out
  _Float16* P3 = (_Float16*)(ws + 3145728);    // [3][B,256,L] f16 pw out
  _Float16* Qt = (_Float16*)(ws + 9437184);    // [64bh][L][32c] f16
  _Float16* Kt = (_Float16*)(ws + 11534336);   // [64bh][L][32c] f16
  _Float16* Vt = (_Float16*)(ws + 13631488);   // [64bh][32c][L] f16

  k_enc<<<2048, 256, 0, stream>>>(x, enc_W, enc_b, X);

  for (int d = 0; d < DD; ++d) {
    k_pw3<<<dim3(2048, 3), 256, 0, stream>>>(X, pw_q + d * CHH * CC,
                                             pw_k + d * CHH * CC,
                                             pw_v + d * CHH * CC, P3);
    k_dwt3<<<dim3(1024, 3), 256, 0, stream>>>(P3,
        dw3_q + d * CHH * 3, dw15_q + d * CHH * 15, gate_q + d * 2,
        dw3_k + d * CHH * 3, dw15_k + d * CHH * 15, gate_k + d * 2,
        dw3_v + d * CHH * 3, dw15_v + d * CHH * 15, gate_v + d * 2,
        Qt, Kt, Vt);
    k_attn<<<dim3(8, 64), 512, 0, stream>>>(Qt, Kt, Vt, AO);
    k_uni_res<<<256, 256, 0, stream>>>(AO, uni_W + d * CC * CHH,
                                       uni_b + d * CC, X, Y);
    k_inorm<<<256, 256, 0, stream>>>(Y, X, n1_g + d * CC, n1_b + d * CC);
    k_ffn<<<256, 256, 0, stream>>>(X, ffn_W1 + d * 128 * CC, ffn_b1 + d * 128,
                                   ffn_W2 + d * CC * 128, ffn_b2 + d * CC, Y);
    k_inorm<<<256, 256, 0, stream>>>(Y, X, n2_g + d * CC, n2_b + d * CC);
  }

  k_cls<<<64, 256, 0, stream>>>(X, cls_W, cls_b, (float*)d_out);
}

// Round 12
// 1120.915 us; speedup vs baseline: 1.4979x; 1.0860x over previous
//
#include <hip/hip_runtime.h>
#include <math.h>

#define LL   2048
#define BB   8
#define CC   32
#define CHH  256
#define HH   8
#define DD   6

typedef _Float16 h8 __attribute__((ext_vector_type(8)));
typedef _Float16 h4 __attribute__((ext_vector_type(4)));
typedef float f4 __attribute__((ext_vector_type(4)));

// ---------------------------------------------------------------- encoder
__global__ __launch_bounds__(256) void k_enc(const float* __restrict__ x,
    const float* __restrict__ W, const float* __restrict__ bias,
    float* __restrict__ X) {
  int idx = blockIdx.x * 256 + threadIdx.x;          // B*32*L = 524288
  int l = idx & (LL - 1);
  int c = (idx >> 11) & 31;
  int b = idx >> 16;
  float s = bias[c];
#pragma unroll
  for (int i = 0; i < 6; ++i)
    s = fmaf(W[c * 6 + i], x[((size_t)b * 6 + i) * LL + l], s);
  X[idx] = s;
}

// -------------------------------- pointwise conv, f16 out, z = tensor (q/k/v)
__global__ __launch_bounds__(256) void k_pw3(const float* __restrict__ X,
    const float* __restrict__ Wq, const float* __restrict__ Wk,
    const float* __restrict__ Wv, _Float16* __restrict__ P3) {
  int z  = blockIdx.y;
  int bx = blockIdx.x;
  int t  = threadIdx.x;
  int lt = bx & 7;
  int og = (bx >> 3) & 31;
  int b  = bx >> 8;
  int l  = lt * 256 + t;
  const float* W = (z == 0) ? Wq : (z == 1) ? Wk : Wv;
  const float* Xp = X + (size_t)b * CC * LL + l;
  float acc[8];
#pragma unroll
  for (int j = 0; j < 8; ++j) acc[j] = 0.f;
  for (int c = 0; c < CC; ++c) {
    float xv = Xp[(size_t)c * LL];
#pragma unroll
    for (int j = 0; j < 8; ++j)
      acc[j] = fmaf(W[(og * 8 + j) * CC + c], xv, acc[j]);
  }
  _Float16* op = P3 + (size_t)z * 4194304 + ((size_t)b * CHH + og * 8) * LL + l;
#pragma unroll
  for (int j = 0; j < 8; ++j) op[(size_t)j * LL] = (_Float16)acc[j];
}

// ------------- fused depthwise conv3+conv15+gate+cvt+layout
// in: P3 [z][b][256ch][L] f16. out: z=0 Qt [bh][l][32c] (scaled by C^-.5*log2e),
// z=1 Kt same layout, z=2 Vt [bh][32c][l].
__global__ __launch_bounds__(256) void k_dwt3(const _Float16* __restrict__ P3,
    const float* __restrict__ d3q, const float* __restrict__ d15q, const float* __restrict__ gq,
    const float* __restrict__ d3k, const float* __restrict__ d15k, const float* __restrict__ gk,
    const float* __restrict__ d3v, const float* __restrict__ d15v, const float* __restrict__ gv,
    _Float16* __restrict__ Qt, _Float16* __restrict__ Kt, _Float16* __restrict__ Vt) {
  __shared__ __align__(16) char lds[9728 + 10240];
  int z  = blockIdx.y;
  int bx = blockIdx.x;
  int bh = bx >> 4, lt = bx & 15, l0 = lt * 128;
  int b = bh >> 3, h = bh & 7;
  int t = threadIdx.x;
  const float* w3p  = (z == 0) ? d3q  : (z == 1) ? d3k  : d3v;
  const float* w15p = (z == 0) ? d15q : (z == 1) ? d15k : d15v;
  const float* gp   = (z == 0) ? gq   : (z == 1) ? gk   : gv;

  {
    int row = t >> 3;
    int j0 = (t & 7) * 9;
    const unsigned int* grow = (const unsigned int*)
        (P3 + ((size_t)z * 8 + b) * (CHH * (size_t)LL) + ((size_t)h * 32 + row) * LL + (l0 - 8));
    unsigned int* lrow = (unsigned int*)(lds + row * 304);
#pragma unroll
    for (int k = 0; k < 9; ++k) {
      int j = j0 + k;
      int l = l0 - 8 + 2 * j;
      unsigned int v = 0;
      if (l >= 0 && l < LL) v = grow[j];
      lrow[j] = v;
    }
  }
  __syncthreads();

  int c = t & 31, cg = t >> 5;
  float wv[32];
  {
    const h8* wp = (const h8*)(lds + c * 304 + cg * 32);
#pragma unroll
    for (int q4 = 0; q4 < 4; ++q4) {
      h8 v = wp[q4];
#pragma unroll
      for (int e = 0; e < 8; ++e) wv[q4 * 8 + e] = (float)v[e];
    }
  }
  float r0 = gp[0], r1 = gp[1];
  float mx = fmaxf(r0, r1);
  float e0 = __expf(r0 - mx), e1 = __expf(r1 - mx);
  float gi = 1.f / (e0 + e1);
  float g0 = e0 * gi, g1 = e1 * gi;
  float sc = (z == 0) ? 0.2550765737f : 1.0f;   // C^-0.5 * log2(e) fold
  int ch = h * 32 + c;
  float w3r[3], w15r[15];
#pragma unroll
  for (int k = 0; k < 3; ++k)  w3r[k]  = w3p[ch * 3 + k];
#pragma unroll
  for (int k = 0; k < 15; ++k) w15r[k] = w15p[ch * 15 + k];

  h8 olo, ohi;
#pragma unroll
  for (int i = 0; i < 16; ++i) {
    float a = 0.f;
#pragma unroll
    for (int k = 0; k < 3; ++k) a = fmaf(w3r[k], wv[i + 7 + k], a);
    float s15 = 0.f;
#pragma unroll
    for (int k = 0; k < 15; ++k) s15 = fmaf(w15r[k], wv[i + 1 + k], s15);
    float val = (g0 * a + g1 * s15) * sc;
    if (i < 8) olo[i] = (_Float16)val; else ohi[i - 8] = (_Float16)val;
  }

  if (z == 2) {
    _Float16* dst = Vt + ((size_t)bh * 32 + c) * LL + l0 + cg * 16;
    *(h8*)dst = olo;
    *(h8*)(dst + 8) = ohi;
  } else {
    char* ot = lds + 9728;
#pragma unroll
    for (int i = 0; i < 16; ++i) {
      _Float16 v = (i < 8) ? olo[i] : ohi[i - 8];
      *(_Float16*)(ot + (cg * 16 + i) * 80 + c * 2) = v;
    }
    __syncthreads();
    _Float16* dst = ((z == 0) ? Qt : Kt) + ((size_t)bh * LL + l0) * 32;
    int l = t >> 1, hf = t & 1;
    uint4 a = *(uint4*)(ot + l * 80 + hf * 32);
    uint4 b2 = *(uint4*)(ot + l * 80 + hf * 32 + 16);
    *(uint4*)(dst + (size_t)l * 32 + hf * 16) = a;
    *(uint4*)(dst + (size_t)l * 32 + hf * 16 + 8) = b2;
  }
}

// ------------------------------------------------ MFMA flash attention (f16)
// In-block key-split: 512 thr = 8 waves; waves 0-3 keys [0,1024), waves 4-7
// keys [1024,2048), same 256 q. Single K/V LDS buffer per segment + register
// prefetch (2 barriers/tile). No-max exp2 softmax; per-q softmax denominator
// computed on the MFMA pipe via ones-row A operand (reuses pf; all C rows
// equal the 32-key column sum -> no VALU adds, no epilogue shuffles).
// Exact in-LDS merge of the two segments (fp32), normalize once, f16 out.
// LDS: K seg*5120 @0; V seg*4608 @10240; P w*5120 @19456 (stride 80: single
// 16B-aligned b128 pf read, 2-way banks = free). Total 60416.
#define KOFF 0
#define VOFF 10240
#define POFF 19456
__global__ __launch_bounds__(512, 2) void k_attn(
    const _Float16* __restrict__ Qt, const _Float16* __restrict__ Kt,
    const _Float16* __restrict__ Vt, _Float16* __restrict__ AO) {
  __shared__ __align__(16) char lds[60416];
  const int tid  = threadIdx.x;
  const int lane = tid & 63;
  const int w    = tid >> 6;                   // 0..7
  const int seg  = w >> 2;                     // 0..1: key segment
  const int wq   = w & 3;                      // q sub-block within 256
  const int g    = lane >> 4;
  const int ln   = lane & 15;
  const int h2c  = (wq >> 1) * 2;
  const int qb   = blockIdx.x;                 // 0..7
  const int bh   = blockIdx.y;                 // 0..63
  const _Float16* Qg = Qt + ((size_t)bh * LL + qb * 256) * 32;
  const _Float16* Kg = Kt + ((size_t)bh * LL + seg * 1024) * 32;
  const _Float16* Vg = Vt + (size_t)bh * 32 * LL + seg * 1024;

  // Q fragments from global (B operand: [k=c][n=q])
  h8 qf[4];
#pragma unroll
  for (int nt = 0; nt < 4; ++nt)
    qf[nt] = *(const h8*)(Qg + (size_t)(wq * 64 + nt * 16 + ln) * 32 + g * 8);

  h8 ones;
#pragma unroll
  for (int j = 0; j < 8; ++j) ones[j] = (_Float16)1.0f;

  char* kb = lds + KOFF + seg * 5120;
  char* vb = lds + VOFF + seg * 4608;
  char* pw = lds + POFF + w * 5120;

  // ---- tile 0 -> regs -> LDS
  uint4 stg0, stg1;
  if ((wq & 1) == 0) {
    const uint4* gk = (const uint4*)Kg;
    stg0 = gk[h2c * 64 + lane];
    stg1 = gk[(h2c + 1) * 64 + lane];
    *(uint4*)(kb + (h2c * 16 + (lane >> 2)) * 80 + (lane & 3) * 16) = stg0;
    *(uint4*)(kb + ((h2c + 1) * 16 + (lane >> 2)) * 80 + (lane & 3) * 16) = stg1;
  } else {
    int c0 = h2c * 8 + (lane >> 3);
    stg0 = *(const uint4*)(Vg + (size_t)c0 * LL + (lane & 7) * 8);
    stg1 = *(const uint4*)(Vg + (size_t)(c0 + 8) * LL + (lane & 7) * 8);
    *(uint4*)(vb + c0 * 144 + (lane & 7) * 16) = stg0;
    *(uint4*)(vb + (c0 + 8) * 144 + (lane & 7) * 16) = stg1;
  }
  __syncthreads();

  f4 o[2][4];
#pragma unroll
  for (int ct = 0; ct < 2; ++ct)
#pragma unroll
    for (int nt = 0; nt < 4; ++nt) o[ct][nt] = (f4){0.f, 0.f, 0.f, 0.f};
  f4 sacc[4];                                  // per-q softmax denom (MFMA)
#pragma unroll
  for (int nt = 0; nt < 4; ++nt) sacc[nt] = (f4){0.f, 0.f, 0.f, 0.f};

  for (int it = 0; it < 16; ++it) {
    if (it < 15) {                             // prefetch next tile to regs
      int k0n = (it + 1) * 64;
      if ((wq & 1) == 0) {
        const uint4* gk = (const uint4*)(Kg + (size_t)k0n * 32);
        stg0 = gk[h2c * 64 + lane];
        stg1 = gk[(h2c + 1) * 64 + lane];
      } else {
        int c0 = h2c * 8 + (lane >> 3);
        stg0 = *(const uint4*)(Vg + (size_t)c0 * LL + k0n + (lane & 7) * 8);
        stg1 = *(const uint4*)(Vg + (size_t)(c0 + 8) * LL + k0n + (lane & 7) * 8);
      }
    }
#pragma unroll
    for (int chunk = 0; chunk < 2; ++chunk) {
      f4 st[2][4];
#pragma unroll
      for (int mt2 = 0; mt2 < 2; ++mt2) {
        h8 kf = *(const h8*)(kb + ((chunk * 2 + mt2) * 16 + ln) * 80 + g * 16);
#pragma unroll
        for (int nt = 0; nt < 4; ++nt) {
          f4 z = {0.f, 0.f, 0.f, 0.f};
          st[mt2][nt] = __builtin_amdgcn_mfma_f32_16x16x32_f16(kf, qf[nt], z, 0, 0, 0);
        }
      }
#pragma unroll
      for (int mt2 = 0; mt2 < 2; ++mt2)
#pragma unroll
        for (int nt = 0; nt < 4; ++nt) {
          float p0 = exp2f(st[mt2][nt][0]);
          float p1 = exp2f(st[mt2][nt][1]);
          float p2 = exp2f(st[mt2][nt][2]);
          float p3 = exp2f(st[mt2][nt][3]);
          unsigned lo = __builtin_bit_cast(unsigned, __builtin_amdgcn_cvt_pkrtz(p0, p1));
          unsigned hi = __builtin_bit_cast(unsigned, __builtin_amdgcn_cvt_pkrtz(p2, p3));
          uint2 pk; pk.x = lo; pk.y = hi;
          *(uint2*)(pw + (nt * 16 + ln) * 80 + mt2 * 32 + g * 8) = pk;
        }
      h8 vf[2];
#pragma unroll
      for (int ct = 0; ct < 2; ++ct)
        vf[ct] = *(const h8*)(vb + (ct * 16 + ln) * 144 + chunk * 64 + g * 16);
#pragma unroll
      for (int nt = 0; nt < 4; ++nt) {
        h8 pf = *(const h8*)(pw + (nt * 16 + ln) * 80 + g * 16);
        sacc[nt] = __builtin_amdgcn_mfma_f32_16x16x32_f16(ones, pf, sacc[nt], 0, 0, 0);
#pragma unroll
        for (int ct = 0; ct < 2; ++ct)
          o[ct][nt] = __builtin_amdgcn_mfma_f32_16x16x32_f16(vf[ct], pf,
                                                             o[ct][nt], 0, 0, 0);
      }
    }
    __syncthreads();                           // everyone done reading K/V LDS
    if (it < 15) {                             // regs -> LDS (same buffer)
      if ((wq & 1) == 0) {
        *(uint4*)(kb + (h2c * 16 + (lane >> 2)) * 80 + (lane & 3) * 16) = stg0;
        *(uint4*)(kb + ((h2c + 1) * 16 + (lane >> 2)) * 80 + (lane & 3) * 16) = stg1;
      } else {
        int c0 = h2c * 8 + (lane >> 3);
        *(uint4*)(vb + c0 * 144 + (lane & 7) * 16) = stg0;
        *(uint4*)(vb + (c0 + 8) * 144 + (lane & 7) * 16) = stg1;
      }
      __syncthreads();                         // staged
    }
  }

  // ---- per-segment denominators: every lane already holds the full sum for
  //      its q=ln in sacc[nt][0] (all C rows identical under ones-A).
  // ---- in-LDS merge: seg1 publishes o (32 f32) + sums (4 f32), lane stride
  //      144 B (2-way banks = free, 16B aligned), region = P space.
  if (seg == 1) {
    char* eo = lds + POFF + wq * 9216 + lane * 144;
#pragma unroll
    for (int nt = 0; nt < 4; ++nt)
#pragma unroll
      for (int ct = 0; ct < 2; ++ct)
        *(f4*)(eo + (nt * 2 + ct) * 16) = o[ct][nt];
    f4 sv;
    sv[0] = sacc[0][0]; sv[1] = sacc[1][0];
    sv[2] = sacc[2][0]; sv[3] = sacc[3][0];
    *(f4*)(eo + 128) = sv;
  }
  __syncthreads();
  if (seg == 0) {
    const char* po = lds + POFF + wq * 9216 + lane * 144;
    f4 s1v = *(const f4*)(po + 128);
    _Float16* out = AO + (size_t)bh * (32 * LL);
#pragma unroll
    for (int nt = 0; nt < 4; ++nt) {
      float inv = 1.f / (sacc[nt][0] + s1v[nt]);
      int qg = qb * 256 + wq * 64 + nt * 16 + ln;
#pragma unroll
      for (int ct = 0; ct < 2; ++ct) {
        f4 o1 = *(const f4*)(po + (nt * 2 + ct) * 16);
#pragma unroll
        for (int r = 0; r < 4; ++r)
          out[(size_t)(ct * 16 + g * 4 + r) * LL + qg] =
              (_Float16)((o[ct][nt][r] + o1[r]) * inv);
      }
    }
  }
}

// -------- uni GEMM [32,256] f16-in + bias + residual; L-split 16, cc-split 2
__global__ __launch_bounds__(256) void k_uni_res(const _Float16* __restrict__ AO,
    const float* __restrict__ W, const float* __restrict__ bias,
    const float* __restrict__ Xin, float* __restrict__ Y) {
  __shared__ float ps[128 * 17];
  int t    = threadIdx.x;
  int li   = t & 127;
  int cg   = t >> 7;                            // 0..1: channel half
  int bx   = blockIdx.x;                        // 256 blocks
  int lt   = bx & 15;
  int half = (bx >> 4) & 1;
  int b    = bx >> 5;
  int l    = lt * 128 + li;
  const _Float16* ap = AO + (size_t)b * CHH * LL + cg * 128 * (size_t)LL + l;
  float acc[16];
#pragma unroll
  for (int j = 0; j < 16; ++j) acc[j] = 0.f;
  for (int cc = 0; cc < 128; cc += 4) {
    float a0 = (float)ap[(size_t)(cc + 0) * LL];
    float a1 = (float)ap[(size_t)(cc + 1) * LL];
    float a2 = (float)ap[(size_t)(cc + 2) * LL];
    float a3 = (float)ap[(size_t)(cc + 3) * LL];
#pragma unroll
    for (int j = 0; j < 16; ++j) {
      const float* wr = W + (half * 16 + j) * CHH + cg * 128 + cc;
      acc[j] = fmaf(wr[0], a0, acc[j]);
      acc[j] = fmaf(wr[1], a1, acc[j]);
      acc[j] = fmaf(wr[2], a2, acc[j]);
      acc[j] = fmaf(wr[3], a3, acc[j]);
    }
  }
  if (cg) {
#pragma unroll
    for (int j = 0; j < 16; ++j) ps[li * 17 + j] = acc[j];
  }
  __syncthreads();
  if (!cg) {
#pragma unroll
    for (int j = 0; j < 16; ++j) {
      int c = half * 16 + j;
      size_t o = ((size_t)b * CC + c) * LL + l;
      Y[o] = acc[j] + ps[li * 17 + j] + bias[c] + Xin[o];
    }
  }
}

// ---------------------------------------------------------- instance norm
__global__ __launch_bounds__(256) void k_inorm(const float* __restrict__ Y,
    float* __restrict__ X, const float* __restrict__ g,
    const float* __restrict__ bt) {
  __shared__ float red[8];
  int row = blockIdx.x;
  int c = row & 31;
  const float* y = Y + (size_t)row * LL;
  float v[8];
  float s = 0.f, ss = 0.f;
#pragma unroll
  for (int i = 0; i < 8; ++i) {
    v[i] = y[threadIdx.x + 256 * i];
    s += v[i];
    ss = fmaf(v[i], v[i], ss);
  }
#pragma unroll
  for (int off = 32; off; off >>= 1) {
    s  += __shfl_down(s, off);
    ss += __shfl_down(ss, off);
  }
  int wid = threadIdx.x >> 6;
  if ((threadIdx.x & 63) == 0) { red[wid * 2] = s; red[wid * 2 + 1] = ss; }
  __syncthreads();
  if (threadIdx.x == 0) {
    red[0] = red[0] + red[2] + red[4] + red[6];
    red[1] = red[1] + red[3] + red[5] + red[7];
  }
  __syncthreads();
  float mean = red[0] * (1.f / LL);
  float var  = red[1] * (1.f / LL) - mean * mean;
  float rs = rsqrtf(var + 1e-5f) * g[c];
  float bb = bt[c];
#pragma unroll
  for (int i = 0; i < 8; ++i)
    X[(size_t)row * LL + threadIdx.x + 256 * i] = (v[i] - mean) * rs + bb;
}

// -------- fused FFN: relu(W1 x + b1) -> W2 + b2 + residual; 64-l tiles,
// 4 o-groups in-block combined via LDS. grid 256.
__global__ __launch_bounds__(256) void k_ffn(const float* __restrict__ X,
    const float* __restrict__ W1, const float* __restrict__ b1,
    const float* __restrict__ W2, const float* __restrict__ b2,
    float* __restrict__ Y) {
  __shared__ float ps[3][64 * 33];
  int bx = blockIdx.x;                          // 8b * 32lt
  int b = bx >> 5;
  int l0 = (bx & 31) * 64;
  int t = threadIdx.x;
  int li = t & 63;
  int og = t >> 6;                              // 0..3
  int l = l0 + li;
  const float* Xp = X + (size_t)b * CC * LL + l;
  float xv[32];
#pragma unroll
  for (int c = 0; c < 32; ++c) xv[c] = Xp[(size_t)c * LL];
  float acc[32];
#pragma unroll
  for (int c = 0; c < 32; ++c) acc[c] = 0.f;
  for (int o = og * 32; o < og * 32 + 32; ++o) {
    float hs = b1[o];
#pragma unroll
    for (int c = 0; c < 32; ++c) hs = fmaf(W1[o * 32 + c], xv[c], hs);
    hs = fmaxf(hs, 0.f);
#pragma unroll
    for (int c = 0; c < 32; ++c) acc[c] = fmaf(W2[c * 128 + o], hs, acc[c]);
  }
  if (og) {
#pragma unroll
    for (int c = 0; c < 32; ++c) ps[og - 1][li * 33 + c] = acc[c];
  }
  __syncthreads();
  if (!og) {
    float* Yp = Y + (size_t)b * CC * LL + l;
#pragma unroll
    for (int c = 0; c < 32; ++c)
      Yp[(size_t)c * LL] = acc[c] + ps[0][li * 33 + c] + ps[1][li * 33 + c] +
                           ps[2][li * 33 + c] + b2[c] + xv[c];
  }
}

// ------------------------------------------------------------- classifier
__global__ __launch_bounds__(256) void k_cls(const float* __restrict__ X,
    const float* __restrict__ W, const float* __restrict__ bias,
    float* __restrict__ out) {
  int idx = blockIdx.x * 256 + threadIdx.x;
  int l = idx & (LL - 1);
  int b = idx >> 11;
  float s = bias[0];
#pragma unroll
  for (int c = 0; c < CC; ++c)
    s = fmaf(W[c], X[((size_t)b * CC + c) * LL + l], s);
  out[idx] = 1.f / (1.f + __expf(-s));
}

// ------------------------------------------------------------------ launch
extern "C" void kernel_launch(void* const* d_in, const int* in_sizes, int n_in,
                              void* d_out, int out_size, void* d_ws,
                              size_t ws_size, hipStream_t stream) {
  const float* x      = (const float*)d_in[0];
  const float* enc_W  = (const float*)d_in[1];
  const float* enc_b  = (const float*)d_in[2];
  const float* pw_q   = (const float*)d_in[3];
  const float* dw3_q  = (const float*)d_in[4];
  const float* dw15_q = (const float*)d_in[5];
  const float* gate_q = (const float*)d_in[6];
  const float* pw_k   = (const float*)d_in[7];
  const float* dw3_k  = (const float*)d_in[8];
  const float* dw15_k = (const float*)d_in[9];
  const float* gate_k = (const float*)d_in[10];
  const float* pw_v   = (const float*)d_in[11];
  const float* dw3_v  = (const float*)d_in[12];
  const float* dw15_v = (const float*)d_in[13];
  const float* gate_v = (const float*)d_in[14];
  const float* uni_W  = (const float*)d_in[15];
  const float* uni_b  = (const float*)d_in[16];
  const float* n1_g   = (const float*)d_in[17];
  const float* n1_b   = (const float*)d_in[18];
  const float* n2_g   = (const float*)d_in[19];
  const float* n2_b   = (const float*)d_in[20];
  const float* ffn_W1 = (const float*)d_in[21];
  const float* ffn_b1 = (const float*)d_in[22];
  const float* ffn_W2 = (const float*)d_in[23];
  const float* ffn_b2 = (const float*)d_in[24];
  const float* cls_W  = (const float*)d_in[25];
  const float* cls_b  = (const float*)d_in[26];

  float* ws = (float*)d_ws;
  float* X   = ws;                             // [B,32,L] fp32
  float* Y   = ws + 524288;                    // [B,32,L] fp32
  _Float16* AO = (_Float16*)(ws + 1048576);    // [B,256,L] f16 attn out
  _Float16* P3 = (_Float16*)(ws + 3145728);    // [3][B,256,L] f16 pw out
  _Float16* Qt = (_Float16*)(ws + 9437184);    // [64bh][L][32c] f16
  _Float16* Kt = (_Float16*)(ws + 11534336);   // [64bh][L][32c] f16
  _Float16* Vt = (_Float16*)(ws + 13631488);   // [64bh][32c][L] f16

  k_enc<<<2048, 256, 0, stream>>>(x, enc_W, enc_b, X);

  for (int d = 0; d < DD; ++d) {
    k_pw3<<<dim3(2048, 3), 256, 0, stream>>>(X, pw_q + d * CHH * CC,
                                             pw_k + d * CHH * CC,
                                             pw_v + d * CHH * CC, P3);
    k_dwt3<<<dim3(1024, 3), 256, 0, stream>>>(P3,
        dw3_q + d * CHH * 3, dw15_q + d * CHH * 15, gate_q + d * 2,
        dw3_k + d * CHH * 3, dw15_k + d * CHH * 15, gate_k + d * 2,
        dw3_v + d * CHH * 3, dw15_v + d * CHH * 15, gate_v + d * 2,
        Qt, Kt, Vt);
    k_attn<<<dim3(8, 64), 512, 0, stream>>>(Qt, Kt, Vt, AO);
    k_uni_res<<<256, 256, 0, stream>>>(AO, uni_W + d * CC * CHH,
                                       uni_b + d * CC, X, Y);
    k_inorm<<<256, 256, 0, stream>>>(Y, X, n1_g + d * CC, n1_b + d * CC);
    k_ffn<<<256, 256, 0, stream>>>(X, ffn_W1 + d * 128 * CC, ffn_b1 + d * 128,
                                   ffn_W2 + d * CC * 128, ffn_b2 + d * CC, Y);
    k_inorm<<<256, 256, 0, stream>>>(Y, X, n2_g + d * CC, n2_b + d * CC);
  }

  k_cls<<<64, 256, 0, stream>>>(X, cls_W, cls_b, (float*)d_out);
}